// Round 4
// baseline (1055.168 us; speedup 1.0000x reference)
//
#include <hip/hip_runtime.h>
#include <cstdint>

typedef __bf16 bf16_t;
typedef __attribute__((ext_vector_type(8))) __bf16 bf16x8;
typedef __attribute__((ext_vector_type(4))) __bf16 bf16x4;
typedef __attribute__((ext_vector_type(4))) float f32x4;

#define MFMA16(a,b,c) __builtin_amdgcn_mfma_f32_16x16x32_bf16((a),(b),(c),0,0,0)

// ---------------- workspace offsets (float units) ----------------
constexpr size_t o_wcatT = 0;                    // bf16 [448][768]
constexpr size_t o_whfT  = o_wcatT + 172032;     // bf16 [128][256]
constexpr size_t o_whvT  = o_whfT  + 16384;      // bf16 [128][512]
constexpr size_t o_WvT   = o_whvT  + 32768;      // bf16 [512][256]
constexpr size_t o_whh   = o_WvT   + 65536;      // f32  [64][66]
constexpr size_t o_keyb  = o_whh   + 4224;       // bf16 [B*T*1024][64]
constexpr size_t o_ms    = o_keyb  + 1048576;    // f32  [B*T*1024]
constexpr size_t o_qeb   = o_ms    + 32768;      // bf16 [B*T*1024][64]
constexpr size_t o_f16b  = o_qeb   + 1048576;    // bf16 [B*T*1024][256]
constexpr size_t o_qfb   = o_f16b  + 4194304;    // bf16 [B*T*1024][160]
constexpr size_t o_kfb   = o_qfb   + 2621440;    // bf16 [B*3072][160]
constexpr size_t o_vb    = o_kfb   + 491520;     // bf16 [B*3072][512]
constexpr size_t o_vhT   = o_vb    + 1572864;    // bf16 [B][128][3072]
constexpr size_t o_pv    = o_vhT   + 393216;     // f32  [B][5][1024][72]
constexpr size_t o_p16   = o_pv    + 737280;     // bf16 [B*T*1024][72]
constexpr size_t o_mh    = o_p16   + 1179648;    // f32  [B][15][1024][66]
constexpr size_t o_hid   = o_mh    + 2027520;    // f32  [B][1024][64]
constexpr size_t o_wmk   = o_hid   + 131072;     // f32  [B][1024]
constexpr size_t ws_need = o_wmk   + 2048;

// ---------------- init: transposed bf16 weight panels ----------------
__global__ __launch_bounds__(256)
void k_init(const float* __restrict__ Wk, const float* __restrict__ Wsh,
            const float* __restrict__ Wse, const float* __restrict__ Wf,
            const float* __restrict__ Wv, const float* __restrict__ Whd,
            const float* __restrict__ Wdec,
            bf16_t* __restrict__ wcatT, bf16_t* __restrict__ whfT,
            bf16_t* __restrict__ whvT, bf16_t* __restrict__ WvT,
            float* __restrict__ whh)
{
    int idx = blockIdx.x*256 + threadIdx.x;
    if (idx < 344064) {                       // wcatT[n][k] n<448 k<768
        int n = idx/768, k = idx%768;
        float v = 0.f;
        if (n < 64)       v = Wk[k*64+n];
        else if (n == 64) v = Wsh[k];
        else if (n < 129) v = Wse[k*64+(n-65)];
        else if (n < 385) v = Wf[k*256+(n-129)];
        wcatT[idx] = (bf16_t)v;
        return;
    }
    idx -= 344064;
    if (idx < 32768) {                        // whfT[c][k] c<128 k<256
        int c = idx/256, k = idx%256;
        float v = 0.f;
        if (c < 64) v = Whd[k*64+c]; else if (c == 64) v = Wdec[k];
        whfT[idx] = (bf16_t)v;
        return;
    }
    idx -= 32768;
    if (idx < 65536) {                        // whvT[c][k] c<128 k<512
        int c = idx/512, k = idx%512;
        float v = 0.f;
        if (c < 64) v = Whd[(256+k)*64+c]; else if (c == 64) v = Wdec[256+k];
        whvT[idx] = (bf16_t)v;
        return;
    }
    idx -= 65536;
    if (idx < 131072) {                       // WvT[n][k] n<512 k<256
        int n = idx/256, k = idx%256;
        WvT[idx] = (bf16_t)Wv[k*512+n];
        return;
    }
    idx -= 131072;
    if (idx < 4224) {                         // whh[k][c] (stride 66), c<65 real
        int k = idx/66, c = idx%66;
        float v = 0.f;
        if (c < 64) v = Whd[(768+k)*64+c]; else if (c == 64) v = Wdec[768+k];
        whh[idx] = v;
    }
}

// ---------------- projection GEMM (MFMA, coalesced fused patchify) ----------------
// grid (16, 32): x = p-tile(64 rows), y = bt. Each block computes all 448 cols.
// A read from HBM exactly once: per K-chunk(32) the block needs 4 image rows
// (i in {i0,i0+1} x pi in {pi0,pi0+1}), each 512 contiguous floats.
__global__ __launch_bounds__(256)
void k_proj(const float* __restrict__ frames, const bf16_t* __restrict__ wcatT,
            bf16_t* __restrict__ keyb, float* __restrict__ msb,
            bf16_t* __restrict__ qeb, bf16_t* __restrict__ f16b)
{
    const int bt = blockIdx.y;
    const int p0 = blockIdx.x*64, i0 = p0 >> 5;
    const int tid = threadIdx.x, lane = tid & 63, w = tid >> 6;
    const int l15 = lane & 15, l4 = lane >> 4;
    __shared__ __align__(16) bf16_t Al[64][40];
    f32x4 acc[4][7] = {};
    const float* fb = frames + (size_t)bt*786432;
    // loader mapping: yi = wave (4 rows y), xq = lane (8 consecutive floats)
    const int yi = w, xq = lane;
    const int jj = xq >> 1, pjh = (xq & 1)*8;
    const int ldsrow = (yi & 1)*32 + jj, ldscol = (yi >> 1)*16 + pjh;
    const int ybase = (i0 + (yi & 1))*16 + (yi >> 1);

    for (int kc = 0; kc < 24; kc++) {
        int k0 = kc*32;
        int c = k0 >> 8, pi0 = (k0 & 255) >> 4;
        const float* src = fb + (size_t)c*262144 + (size_t)(ybase + pi0)*512 + xq*8;
        float4 v0 = *(const float4*)src;
        float4 v1 = *(const float4*)(src + 4);
        __syncthreads();
        bf16x8 pk;
        pk[0]=(bf16_t)v0.x; pk[1]=(bf16_t)v0.y; pk[2]=(bf16_t)v0.z; pk[3]=(bf16_t)v0.w;
        pk[4]=(bf16_t)v1.x; pk[5]=(bf16_t)v1.y; pk[6]=(bf16_t)v1.z; pk[7]=(bf16_t)v1.w;
        *(bf16x8*)&Al[ldsrow][ldscol] = pk;
        __syncthreads();
        bf16x8 am[4];
        #pragma unroll
        for (int fi = 0; fi < 4; fi++)
            am[fi] = *(const bf16x8*)&Al[fi*16 + l15][l4*8];
        #pragma unroll
        for (int fj = 0; fj < 7; fj++) {
            int n = w*112 + fj*16 + l15;
            bf16x8 bv = *(const bf16x8*)(wcatT + (size_t)n*768 + k0 + l4*8);
            #pragma unroll
            for (int fi = 0; fi < 4; fi++)
                acc[fi][fj] = MFMA16(am[fi], bv, acc[fi][fj]);
        }
    }
    #pragma unroll
    for (int fi = 0; fi < 4; fi++)
    #pragma unroll
    for (int fj = 0; fj < 7; fj++) {
        int nn = w*112 + fj*16 + l15;
        #pragma unroll
        for (int r = 0; r < 4; r++) {
            int pp = p0 + fi*16 + l4*4 + r;
            float v = acc[fi][fj][r];
            size_t rowb = (size_t)bt*1024 + pp;
            if (nn < 64)       keyb[rowb*64 + nn] = (bf16_t)v;
            else if (nn == 64) msb[rowb] = v*v + 1.f;
            else if (nn < 129) qeb[rowb*64 + (nn-65)] = (bf16_t)(1.f/(1.f+expf(-v)));
            else if (nn < 385) f16b[rowb*256 + (nn-129)] = (bf16_t)v;
        }
    }
}

// ---------------- Qfeat: [qe*qk | qe | b_sq | zeros] bf16 ----------------
// grid (32, 128), block (64,8)
__global__ __launch_bounds__(512)
void k_qf(const bf16_t* __restrict__ keyb, const bf16_t* __restrict__ qeb,
          bf16_t* __restrict__ qfb)
{
    int bt = blockIdx.x;
    int p = blockIdx.y*8 + threadIdx.y;
    int c = threadIdx.x;
    size_t rowb = (size_t)bt*1024 + p;
    float qk = (float)keyb[rowb*64 + c];
    float qv = (float)qeb[rowb*64 + c];
    float bsq = qv*qk*qk;
    #pragma unroll
    for (int off = 32; off; off >>= 1) bsq += __shfl_xor(bsq, off);
    bf16_t* q = qfb + rowb*160;
    q[c]      = (bf16_t)(qv*qk);
    q[64 + c] = (bf16_t)qv;
    if (c == 0) q[128] = (bf16_t)bsq;
    if (c < 31) q[129 + c] = (bf16_t)0.f;
}

// ---------------- Kfeat rows for a memory slot ----------------
// grid (2, 128), block (64,8)
__global__ __launch_bounds__(512)
void k_kf(const bf16_t* __restrict__ keyb, const float* __restrict__ msb,
          bf16_t* __restrict__ kfb, int tm, int slot)
{
    int b = blockIdx.x;
    int p = blockIdx.y*8 + threadIdx.y;
    int c = threadIdx.x;
    size_t rowb = (size_t)(b*16 + tm)*1024 + p;
    float mk = (float)keyb[rowb*64 + c];
    float m  = msb[rowb];
    bf16_t* kr = kfb + ((size_t)b*3072 + slot*1024 + p)*160;
    kr[c]      = (bf16_t)( m*mk*0.25f);
    kr[64 + c] = (bf16_t)(-m*mk*mk*0.125f);
    if (c == 0) kr[128] = (bf16_t)(-m*0.125f);
    if (c < 31) kr[129 + c] = (bf16_t)0.f;
}

// ---------------- t=0 mask: aggregate + 16x16 avg-pool (coalesced) ----------------
// grid 64 (b*32+i), block 256. sigmoid(l1-l0) == pc^2/(pc^2+qc^2).
__global__ __launch_bounds__(256)
void k_mask0(const float* __restrict__ im, float* __restrict__ wmask)
{
    int blk = blockIdx.x;
    int b = blk >> 5, i = blk & 31;
    int tid = threadIdx.x;
    int xq = tid & 127, yh = tid >> 7;
    const float* base = im + (size_t)b*262144 + (size_t)(i*16)*512;
    float s = 0.f;
    for (int yy = 0; yy < 8; yy++) {
        int y = yy*2 + yh;
        float4 v = *(const float4*)(base + (size_t)y*512 + xq*4);
        float e[4] = {v.x, v.y, v.z, v.w};
        #pragma unroll
        for (int u = 0; u < 4; u++) {
            float pc = fminf(fmaxf(e[u],      1e-7f), 1.f-1e-7f);
            float qc = fminf(fmaxf(1.f-e[u],  1e-7f), 1.f-1e-7f);
            s += pc*pc/(pc*pc + qc*qc);
        }
    }
    __shared__ float red[32];
    if (tid < 32) red[tid] = 0.f;
    __syncthreads();
    atomicAdd(&red[xq >> 2], s);
    __syncthreads();
    if (tid < 32) wmask[b*1024 + i*32 + tid] = red[tid]*(1.f/256.f);
}

// ---------------- value (MFMA): V = f16 @ Wv[0:256] + wmask*Wv[256] ----------------
// grid (8, 16, 2), block 256
__global__ __launch_bounds__(256)
void k_value(const bf16_t* __restrict__ f16b, const float* __restrict__ wmk,
             const bf16_t* __restrict__ WvT, const float* __restrict__ Wv,
             bf16_t* __restrict__ vb, int t, int slot)
{
    int b = blockIdx.z;
    int n0 = blockIdx.x*64, p0 = blockIdx.y*64;
    const int tid = threadIdx.x, lane = tid & 63, w = tid >> 6;
    const int wr = w >> 1, wc = w & 1, l15 = lane & 15, l4 = lane >> 4;
    const bf16_t* A = f16b + ((size_t)(b*16 + t)*1024 + p0)*256;
    f32x4 acc[2][2] = {};
    int ar = wr*32 + l15, bc = n0 + wc*32 + l15, koff = l4*8;
    #pragma unroll
    for (int ks = 0; ks < 8; ks++) {
        bf16x8 a0 = *(const bf16x8*)(A + (size_t)ar*256 + ks*32 + koff);
        bf16x8 a1 = *(const bf16x8*)(A + (size_t)(ar+16)*256 + ks*32 + koff);
        bf16x8 b0 = *(const bf16x8*)(WvT + (size_t)bc*256 + ks*32 + koff);
        bf16x8 b1 = *(const bf16x8*)(WvT + (size_t)(bc+16)*256 + ks*32 + koff);
        acc[0][0] = MFMA16(a0, b0, acc[0][0]);
        acc[0][1] = MFMA16(a0, b1, acc[0][1]);
        acc[1][0] = MFMA16(a1, b0, acc[1][0]);
        acc[1][1] = MFMA16(a1, b1, acc[1][1]);
    }
    #pragma unroll
    for (int fi = 0; fi < 2; fi++)
    #pragma unroll
    for (int fj = 0; fj < 2; fj++) {
        int nn = n0 + wc*32 + fj*16 + l15;
        float wvl = Wv[131072 + nn];
        #pragma unroll
        for (int r = 0; r < 4; r++) {
            int pp = p0 + wr*32 + fi*16 + l4*4 + r;
            float wm = wmk[b*1024 + pp];
            vb[((size_t)b*3072 + slot*1024 + pp)*512 + nn] = (bf16_t)(acc[fi][fj][r] + wm*wvl);
        }
    }
}

// ---------------- Vh^T (MFMA): vhT[c][n], rows 65..79 zeroed ----------------
// grid (16, 2), block 256, tile 64(n) x 128(c)
__global__ __launch_bounds__(256)
void k_vh(const bf16_t* __restrict__ vb, const bf16_t* __restrict__ whvT,
          bf16_t* __restrict__ vhT, int slot)
{
    int b = blockIdx.y;
    int n0 = blockIdx.x*64;
    const int tid = threadIdx.x, lane = tid & 63, w = tid >> 6;
    const int wr = w >> 1, wc = w & 1, l15 = lane & 15, l4 = lane >> 4;
    const bf16_t* A = vb + ((size_t)b*3072 + slot*1024 + n0)*512;
    f32x4 acc[2][4] = {};
    int ar = wr*32 + l15, koff = l4*8;
    #pragma unroll 4
    for (int ks = 0; ks < 16; ks++) {
        bf16x8 a0 = *(const bf16x8*)(A + (size_t)ar*512 + ks*32 + koff);
        bf16x8 a1 = *(const bf16x8*)(A + (size_t)(ar+16)*512 + ks*32 + koff);
        #pragma unroll
        for (int fj = 0; fj < 4; fj++) {
            int cc = wc*64 + fj*16 + l15;
            bf16x8 bv = *(const bf16x8*)(whvT + (size_t)cc*512 + ks*32 + koff);
            acc[0][fj] = MFMA16(a0, bv, acc[0][fj]);
            acc[1][fj] = MFMA16(a1, bv, acc[1][fj]);
        }
    }
    #pragma unroll
    for (int fi = 0; fi < 2; fi++)
    #pragma unroll
    for (int fj = 0; fj < 4; fj++) {
        int cc = wc*64 + fj*16 + l15;
        if (cc < 80) {
            float vz = (cc < 65) ? 0.f : 0.f;  // keep shape; value picked below
            #pragma unroll
            for (int r = 0; r < 4; r++) {
                int nn = n0 + wr*32 + fi*16 + l4*4 + r;
                float val = (cc < 65) ? acc[fi][fj][r] : 0.f;
                vhT[(size_t)b*393216 + (size_t)cc*3072 + slot*1024 + nn] = (bf16_t)val;
            }
            (void)vz;
        }
    }
}

// ---------------- pre16 (MFMA): f16 @ [Whd_lo|Wdec_lo] -> [p][65] ----------------
// grid (16, 32), block 256, tile 64 x 128
__global__ __launch_bounds__(256)
void k_pre16(const bf16_t* __restrict__ f16b, const bf16_t* __restrict__ whfT,
             bf16_t* __restrict__ p16b)
{
    int bt = blockIdx.y;
    int p0 = blockIdx.x*64;
    const int tid = threadIdx.x, lane = tid & 63, w = tid >> 6;
    const int wr = w >> 1, wc = w & 1, l15 = lane & 15, l4 = lane >> 4;
    const bf16_t* A = f16b + ((size_t)bt*1024 + p0)*256;
    f32x4 acc[2][4] = {};
    int ar = wr*32 + l15, koff = l4*8;
    #pragma unroll
    for (int ks = 0; ks < 8; ks++) {
        bf16x8 a0 = *(const bf16x8*)(A + (size_t)ar*256 + ks*32 + koff);
        bf16x8 a1 = *(const bf16x8*)(A + (size_t)(ar+16)*256 + ks*32 + koff);
        #pragma unroll
        for (int fj = 0; fj < 4; fj++) {
            int cc = wc*64 + fj*16 + l15;
            bf16x8 bv = *(const bf16x8*)(whfT + (size_t)cc*256 + ks*32 + koff);
            acc[0][fj] = MFMA16(a0, bv, acc[0][fj]);
            acc[1][fj] = MFMA16(a1, bv, acc[1][fj]);
        }
    }
    #pragma unroll
    for (int fi = 0; fi < 2; fi++)
    #pragma unroll
    for (int fj = 0; fj < 4; fj++) {
        int cc = wc*64 + fj*16 + l15;
        if (cc < 65) {
            #pragma unroll
            for (int r = 0; r < 4; r++) {
                int pp = p0 + wr*32 + fi*16 + l4*4 + r;
                p16b[((size_t)bt*1024 + pp)*72 + cc] = (bf16_t)acc[fi][fj][r];
            }
        }
    }
}

// ---------------- flash attention: S + online softmax + PV fused ----------------
// grid (16 ptile, 5 ts, 2 b), block 256 = 4 independent waves (16 q-rows each).
// No __syncthreads: P bounces through per-wave-private LDS.
__global__ __launch_bounds__(256)
void k_att(const bf16_t* __restrict__ qfb, const bf16_t* __restrict__ kfb,
           const bf16_t* __restrict__ vhT, float* __restrict__ PV,
           int t0, int N)
{
    int b = blockIdx.z, ts = blockIdx.y, p0 = blockIdx.x*64;
    int t = t0 + ts;
    int tid = threadIdx.x, lane = tid & 63, w = tid >> 6;
    int l15 = lane & 15, l4 = lane >> 4;
    __shared__ __align__(16) bf16_t P_lds[4][16][72];   // stride 144B: 2-way alias (free)

    const bf16_t* Q = qfb + ((size_t)(b*16 + t)*1024 + p0 + w*16 + l15)*160 + l4*8;
    bf16x8 aq[5];
    #pragma unroll
    for (int kc = 0; kc < 5; kc++) aq[kc] = *(const bf16x8*)(Q + kc*32);

    const bf16_t* K  = kfb + (size_t)b*3072*160;
    const bf16_t* Vh = vhT + (size_t)b*393216;
    f32x4 o[5] = {};
    float mrow[4], lrow[4];
    #pragma unroll
    for (int r = 0; r < 4; r++) { mrow[r] = -1e30f; lrow[r] = 0.f; }

    for (int n0 = 0; n0 < N; n0 += 64) {
        f32x4 s[4] = {};
        #pragma unroll
        for (int kc = 0; kc < 5; kc++) {
            #pragma unroll
            for (int nf = 0; nf < 4; nf++) {
                bf16x8 bk = *(const bf16x8*)(K + (size_t)(n0 + nf*16 + l15)*160 + kc*32 + l4*8);
                s[nf] = MFMA16(aq[kc], bk, s[nf]);
            }
        }
        // online softmax; lane holds rows l4*4+r, col l15 (+16*nf)
        #pragma unroll
        for (int r = 0; r < 4; r++) {
            float mx = fmaxf(fmaxf(s[0][r], s[1][r]), fmaxf(s[2][r], s[3][r]));
            #pragma unroll
            for (int off = 1; off < 16; off <<= 1) mx = fmaxf(mx, __shfl_xor(mx, off));
            float mnew = fmaxf(mrow[r], mx);
            float alpha = expf(mrow[r] - mnew);
            float ps = 0.f;
            #pragma unroll
            for (int nf = 0; nf < 4; nf++) {
                float pe = expf(s[nf][r] - mnew);
                s[nf][r] = pe;
                ps += pe;
            }
            #pragma unroll
            for (int off = 1; off < 16; off <<= 1) ps += __shfl_xor(ps, off);
            lrow[r] = lrow[r]*alpha + ps;
            mrow[r] = mnew;
            #pragma unroll
            for (int cf = 0; cf < 5; cf++) o[cf][r] *= alpha;
        }
        // P -> LDS (C-layout scatter), then read back as A-frags
        #pragma unroll
        for (int nf = 0; nf < 4; nf++)
            #pragma unroll
            for (int r = 0; r < 4; r++)
                P_lds[w][l4*4 + r][nf*16 + l15] = (bf16_t)s[nf][r];
        #pragma unroll
        for (int kc2 = 0; kc2 < 2; kc2++) {
            bf16x8 ap = *(const bf16x8*)&P_lds[w][l15][kc2*32 + l4*8];
            #pragma unroll
            for (int cf = 0; cf < 5; cf++) {
                bf16x8 bv = *(const bf16x8*)(Vh + (size_t)(cf*16 + l15)*3072 + n0 + kc2*32 + l4*8);
                o[cf] = MFMA16(ap, bv, o[cf]);
            }
        }
    }
    float* O = PV + ((size_t)((b*5 + ts)*1024) + p0 + w*16)*72;
    #pragma unroll
    for (int cf = 0; cf < 5; cf++) {
        int cc = cf*16 + l15;
        if (cc < 65) {
            #pragma unroll
            for (int r = 0; r < 4; r++)
                O[(size_t)(l4*4 + r)*72 + cc] = o[cf][r]/lrow[r];
        }
    }
}

// ---------------- sequential 5-step chain, one row per wave ----------------
// grid (256, 2), block 256
__global__ __launch_bounds__(256)
void k_chain2(const bf16_t* __restrict__ p16b, const float* __restrict__ PV,
              const float* __restrict__ whhbuf, float* __restrict__ hidden,
              float* __restrict__ wmk, float* __restrict__ mh, int t0, int ph)
{
    int b = blockIdx.y;
    int tid = threadIdx.x, lane = tid & 63, w = tid >> 6;
    int p = blockIdx.x*4 + w;
    __shared__ float whh_s[64][66];
    __shared__ float hid_s[4][64];
    for (int idx = tid; idx < 64*66; idx += 256) whh_s[idx/66][idx%66] = whhbuf[idx];
    float h = hidden[((size_t)b*1024 + p)*64 + lane];
    hid_s[w][lane] = h;
    __syncthreads();
    float wd = whh_s[lane][64];
    for (int ts = 0; ts < 5; ts++) {
        int t = t0 + ts;
        size_t r16 = ((size_t)(b*16 + t)*1024 + p)*72;
        size_t rpv = ((size_t)((b*5 + ts)*1024) + p)*72;
        float pre   = (float)p16b[r16 + lane] + PV[rpv + lane];
        float fgpre = (float)p16b[r16 + 64]   + PV[rpv + 64];
        float s = pre;
        #pragma unroll 8
        for (int k = 0; k < 64; k++) s += hid_s[w][k]*whh_s[k][lane];
        float hl = tanhf(s);
        float fgs = hl*wd;
        #pragma unroll
        for (int off = 1; off < 64; off <<= 1) fgs += __shfl_xor(fgs, off);
        float fg = fgpre + fgs;
        float m = 1.f/(1.f+expf(-fg));
        size_t rmh = ((size_t)(b*15 + ph*5 + ts)*1024 + p)*66;
        mh[rmh + lane] = m*hl;
        if (lane == 0) mh[rmh + 64] = m;
        if (ts == 4 && lane == 0) wmk[b*1024 + p] = m;
        h = hl;
        __syncthreads();
        hid_s[w][lane] = h;
        __syncthreads();
    }
    hidden[((size_t)b*1024 + p)*64 + lane] = h;
}

// ---------------- hidden GEMM (f32 SIMT, small): tanh([V|hid?] @ Wh2) ----------------
// grid (1, 16, 2), block 256
__global__ __launch_bounds__(256)
void k_hid(const bf16_t* __restrict__ vb, const float* __restrict__ Wh2,
           float* __restrict__ hidden, int vslot, int has_h)
{
    int b = blockIdx.z; int p0 = blockIdx.y*64;
    int tid = threadIdx.x, tx = tid & 15, ty = tid >> 4;
    __shared__ float As[16][68], Bs[16][68];
    float acc[4][4] = {};
    const bf16_t* A = vb + ((size_t)b*3072 + vslot*1024)*512;
    const float* Hh = hidden + (size_t)b*1024*64;
    int KK = has_h ? 576 : 512;
    const int kk = tid & 15, rr = tid >> 4, colB = tid & 63, kB = tid >> 6;
    for (int k0 = 0; k0 < KK; k0 += 16) {
        #pragma unroll
        for (int s = 0; s < 4; s++) {
            int row = rr + s*16, p = p0 + row, k = k0 + kk;
            As[kk][row] = (k < 512) ? (float)A[(size_t)p*512 + k] : Hh[(size_t)p*64 + (k-512)];
        }
        #pragma unroll
        for (int s = 0; s < 4; s++) { int kb2 = kB + s*4; Bs[kb2][colB] = Wh2[(size_t)(k0+kb2)*64 + colB]; }
        __syncthreads();
        #pragma unroll
        for (int q = 0; q < 16; q++) {
            float4 av = *(const float4*)&As[q][ty*4];
            float4 bv = *(const float4*)&Bs[q][tx*4];
            float a_[4] = {av.x,av.y,av.z,av.w};
            float b_[4] = {bv.x,bv.y,bv.z,bv.w};
            #pragma unroll
            for (int i = 0; i < 4; i++)
                #pragma unroll
                for (int j = 0; j < 4; j++)
                    acc[i][j] = fmaf(a_[i], b_[j], acc[i][j]);
        }
        __syncthreads();
    }
    #pragma unroll
    for (int i = 0; i < 4; i++) {
        int p = p0 + ty*4 + i;
        #pragma unroll
        for (int j = 0; j < 4; j++)
            hidden[(size_t)(b*1024 + p)*64 + tx*4 + j] = tanhf(acc[i][j]);
    }
}

// ---------------- feat t=0: mean over spatial of key ----------------
__global__ void k_feat0(const bf16_t* __restrict__ keyb, float* __restrict__ out)
{
    int b = blockIdx.x, c = threadIdx.x;
    const bf16_t* kb = keyb + (size_t)(b*16)*1024*64;
    float s = 0.f;
    for (int p = 0; p < 1024; p++) s += (float)kb[(size_t)p*64 + c];
    out[(size_t)(b*16)*64 + c] = s*(1.f/1024.f);
}

// ---------------- feats t=1..15: weighted mean reduce (parallel) ----------------
// grid (15, 2), block 256
__global__ __launch_bounds__(256)
void k_feats(const float* __restrict__ mh, float* __restrict__ out)
{
    int slot = blockIdx.x, b = blockIdx.y, t = slot + 1;
    int tid = threadIdx.x, c = tid & 63, g = tid >> 6;
    const float* base = mh + (size_t)(b*15 + slot)*1024*66;
    float s = 0.f, sm = 0.f;
    for (int p = g; p < 1024; p += 4) {
        s += base[(size_t)p*66 + c];
        if (c == 0) sm += base[(size_t)p*66 + 64];
    }
    __shared__ float red[4][64];
    __shared__ float redm[4];
    red[g][c] = s;
    if (c == 0) redm[g] = sm;
    __syncthreads();
    if (g == 0) {
        float tot  = red[0][c] + red[1][c] + red[2][c] + red[3][c];
        float totm = redm[0] + redm[1] + redm[2] + redm[3];
        out[(size_t)(b*16 + t)*64 + c] = tot / fmaxf(totm, 1e-6f);
    }
}

// ---------------- host launcher ----------------
extern "C" void kernel_launch(void* const* d_in, const int* in_sizes, int n_in,
                              void* d_out, int out_size, void* d_ws, size_t ws_size,
                              hipStream_t stream)
{
    (void)in_sizes; (void)n_in; (void)out_size;
    if (ws_size < ws_need*sizeof(float)) return;
    const float* frames = (const float*)d_in[0];
    const float* imask  = (const float*)d_in[1];
    const float* Wk   = (const float*)d_in[3];
    const float* Wsh  = (const float*)d_in[4];
    const float* Wse  = (const float*)d_in[5];
    const float* Wf   = (const float*)d_in[6];
    const float* Wv   = (const float*)d_in[7];
    const float* Wh2  = (const float*)d_in[8];
    const float* Whd  = (const float*)d_in[9];
    const float* Wdec = (const float*)d_in[10];
    float* out = (float*)d_out;
    float* ws  = (float*)d_ws;

    bf16_t* wcatT = (bf16_t*)(ws + o_wcatT);
    bf16_t* whfT  = (bf16_t*)(ws + o_whfT);
    bf16_t* whvT  = (bf16_t*)(ws + o_whvT);
    bf16_t* WvT   = (bf16_t*)(ws + o_WvT);
    float*  whh   = ws + o_whh;
    bf16_t* keyb  = (bf16_t*)(ws + o_keyb);
    float*  msb   = ws + o_ms;
    bf16_t* qeb   = (bf16_t*)(ws + o_qeb);
    bf16_t* f16b  = (bf16_t*)(ws + o_f16b);
    bf16_t* qfb   = (bf16_t*)(ws + o_qfb);
    bf16_t* kfb   = (bf16_t*)(ws + o_kfb);
    bf16_t* vb    = (bf16_t*)(ws + o_vb);
    bf16_t* vhT   = (bf16_t*)(ws + o_vhT);
    float*  PV    = ws + o_pv;
    bf16_t* p16b  = (bf16_t*)(ws + o_p16);
    float*  mh    = ws + o_mh;
    float*  hid   = ws + o_hid;
    float*  wmk   = ws + o_wmk;

    k_init<<<2257, 256, 0, stream>>>(Wk, Wsh, Wse, Wf, Wv, Whd, Wdec,
                                     wcatT, whfT, whvT, WvT, whh);
    k_proj<<<dim3(16,32), 256, 0, stream>>>(frames, wcatT, keyb, msb, qeb, f16b);
    k_qf<<<dim3(32,128), dim3(64,8), 0, stream>>>(keyb, qeb, qfb);
    k_mask0<<<64, 256, 0, stream>>>(imask, wmk);
    k_kf<<<dim3(2,128), dim3(64,8), 0, stream>>>(keyb, msb, kfb, 0, 0);
    k_value<<<dim3(8,16,2), 256, 0, stream>>>(f16b, wmk, WvT, Wv, vb, 0, 0);
    k_vh<<<dim3(16,2), 256, 0, stream>>>(vb, whvT, vhT, 0);
    k_hid<<<dim3(1,16,2), 256, 0, stream>>>(vb, Wh2, hid, 0, 0);
    k_feat0<<<2, 64, 0, stream>>>(keyb, out);
    k_pre16<<<dim3(16,32), 256, 0, stream>>>(f16b, whfT, p16b);

    const int Ns[3] = {1024, 2048, 3072};
    for (int ph = 0; ph < 3; ph++) {
        int t0 = 1 + ph*5, N = Ns[ph];
        k_att<<<dim3(16,5,2), 256, 0, stream>>>(qfb, kfb, vhT, PV, t0, N);
        k_chain2<<<dim3(256,2), 256, 0, stream>>>(p16b, PV, whh, hid, wmk, mh, t0, ph);
        if (ph < 2) {
            int tm = t0 + 4, slot = ph + 1;
            k_kf<<<dim3(2,128), dim3(64,8), 0, stream>>>(keyb, msb, kfb, tm, slot);
            k_value<<<dim3(8,16,2), 256, 0, stream>>>(f16b, wmk, WvT, Wv, vb, tm, slot);
            k_vh<<<dim3(16,2), 256, 0, stream>>>(vb, whvT, vhT, slot);
            if (ph == 1) k_hid<<<dim3(1,16,2), 256, 0, stream>>>(vb, Wh2, hid, 2, 1);
        }
    }
    k_feats<<<dim3(15,2), 256, 0, stream>>>(mh, out);
}

// Round 5
// 637.431 us; speedup vs baseline: 1.6553x; 1.6553x over previous
//
#include <hip/hip_runtime.h>
#include <cstdint>

typedef __bf16 bf16_t;
typedef __attribute__((ext_vector_type(8))) __bf16 bf16x8;
typedef __attribute__((ext_vector_type(4))) __bf16 bf16x4;
typedef __attribute__((ext_vector_type(4))) float f32x4;

#define MFMA16(a,b,c) __builtin_amdgcn_mfma_f32_16x16x32_bf16((a),(b),(c),0,0,0)

// ---------------- workspace offsets (float units) ----------------
constexpr size_t PVSTR   = (size_t)2*5*1024*72;  // one N-slice of PV partials
constexpr size_t o_wcatT = 0;                    // bf16 [448][768]
constexpr size_t o_whfT  = o_wcatT + 172032;     // bf16 [128][256]
constexpr size_t o_whvT  = o_whfT  + 16384;      // bf16 [128][512]
constexpr size_t o_WvT   = o_whvT  + 32768;      // bf16 [512][256]
constexpr size_t o_whh   = o_WvT   + 65536;      // f32  [64][66]
constexpr size_t o_keyb  = o_whh   + 4224;       // bf16 [B*T*1024][64]
constexpr size_t o_ms    = o_keyb  + 1048576;    // f32  [B*T*1024]
constexpr size_t o_qeb   = o_ms    + 32768;      // bf16 [B*T*1024][64]
constexpr size_t o_f16b  = o_qeb   + 1048576;    // bf16 [B*T*1024][256]
constexpr size_t o_qfb   = o_f16b  + 4194304;    // bf16 [B*T*1024][160]
constexpr size_t o_kfb   = o_qfb   + 2621440;    // bf16 [B*3072][160]
constexpr size_t o_vb    = o_kfb   + 491520;     // bf16 [B*3072][512]
constexpr size_t o_vhT   = o_vb    + 1572864;    // bf16 [B][128][3072] (row65 = ones)
constexpr size_t o_pv    = o_vhT   + 393216;     // f32  [12 slices][B][5][1024][72]
constexpr size_t o_p16   = o_pv    + 12*PVSTR;   // bf16 [B*T*1024][72]
constexpr size_t o_mh    = o_p16   + 1179648;    // f32  [B][15][1024][66]
constexpr size_t o_hid   = o_mh    + 2027520;    // f32  [B][1024][64]
constexpr size_t o_wmk   = o_hid   + 131072;     // f32  [B][1024]
constexpr size_t ws_need = o_wmk   + 2048;

// ---------------- init: transposed bf16 weight panels ----------------
__global__ __launch_bounds__(256)
void k_init(const float* __restrict__ Wk, const float* __restrict__ Wsh,
            const float* __restrict__ Wse, const float* __restrict__ Wf,
            const float* __restrict__ Wv, const float* __restrict__ Whd,
            const float* __restrict__ Wdec,
            bf16_t* __restrict__ wcatT, bf16_t* __restrict__ whfT,
            bf16_t* __restrict__ whvT, bf16_t* __restrict__ WvT,
            float* __restrict__ whh)
{
    int idx = blockIdx.x*256 + threadIdx.x;
    if (idx < 344064) {                       // wcatT[n][k] n<448 k<768
        int n = idx/768, k = idx%768;
        float v = 0.f;
        if (n < 64)       v = Wk[k*64+n];
        else if (n == 64) v = Wsh[k];
        else if (n < 129) v = Wse[k*64+(n-65)];
        else if (n < 385) v = Wf[k*256+(n-129)];
        wcatT[idx] = (bf16_t)v;
        return;
    }
    idx -= 344064;
    if (idx < 32768) {                        // whfT[c][k] c<128 k<256
        int c = idx/256, k = idx%256;
        float v = 0.f;
        if (c < 64) v = Whd[k*64+c]; else if (c == 64) v = Wdec[k];
        whfT[idx] = (bf16_t)v;
        return;
    }
    idx -= 32768;
    if (idx < 65536) {                        // whvT[c][k] c<128 k<512
        int c = idx/512, k = idx%512;
        float v = 0.f;
        if (c < 64) v = Whd[(256+k)*64+c]; else if (c == 64) v = Wdec[256+k];
        whvT[idx] = (bf16_t)v;
        return;
    }
    idx -= 65536;
    if (idx < 131072) {                       // WvT[n][k] n<512 k<256
        int n = idx/256, k = idx%256;
        WvT[idx] = (bf16_t)Wv[k*512+n];
        return;
    }
    idx -= 131072;
    if (idx < 4224) {                         // whh[k][c] (stride 66), c<65 real
        int k = idx/66, c = idx%66;
        float v = 0.f;
        if (c < 64) v = Whd[(768+k)*64+c]; else if (c == 64) v = Wdec[768+k];
        whh[idx] = v;
    }
}

// ---------------- projection GEMM (MFMA, coalesced fused patchify) ----------------
__global__ __launch_bounds__(256)
void k_proj(const float* __restrict__ frames, const bf16_t* __restrict__ wcatT,
            bf16_t* __restrict__ keyb, float* __restrict__ msb,
            bf16_t* __restrict__ qeb, bf16_t* __restrict__ f16b)
{
    const int bt = blockIdx.y;
    const int p0 = blockIdx.x*64, i0 = p0 >> 5;
    const int tid = threadIdx.x, lane = tid & 63, w = tid >> 6;
    const int l15 = lane & 15, l4 = lane >> 4;
    __shared__ __align__(16) bf16_t Al[64][40];
    f32x4 acc[4][7] = {};
    const float* fb = frames + (size_t)bt*786432;
    const int yi = w, xq = lane;
    const int jj = xq >> 1, pjh = (xq & 1)*8;
    const int ldsrow = (yi & 1)*32 + jj, ldscol = (yi >> 1)*16 + pjh;
    const int ybase = (i0 + (yi & 1))*16 + (yi >> 1);

    for (int kc = 0; kc < 24; kc++) {
        int k0 = kc*32;
        int c = k0 >> 8, pi0 = (k0 & 255) >> 4;
        const float* src = fb + (size_t)c*262144 + (size_t)(ybase + pi0)*512 + xq*8;
        float4 v0 = *(const float4*)src;
        float4 v1 = *(const float4*)(src + 4);
        __syncthreads();
        bf16x8 pk;
        pk[0]=(bf16_t)v0.x; pk[1]=(bf16_t)v0.y; pk[2]=(bf16_t)v0.z; pk[3]=(bf16_t)v0.w;
        pk[4]=(bf16_t)v1.x; pk[5]=(bf16_t)v1.y; pk[6]=(bf16_t)v1.z; pk[7]=(bf16_t)v1.w;
        *(bf16x8*)&Al[ldsrow][ldscol] = pk;
        __syncthreads();
        bf16x8 am[4];
        #pragma unroll
        for (int fi = 0; fi < 4; fi++)
            am[fi] = *(const bf16x8*)&Al[fi*16 + l15][l4*8];
        #pragma unroll
        for (int fj = 0; fj < 7; fj++) {
            int n = w*112 + fj*16 + l15;
            bf16x8 bv = *(const bf16x8*)(wcatT + (size_t)n*768 + k0 + l4*8);
            #pragma unroll
            for (int fi = 0; fi < 4; fi++)
                acc[fi][fj] = MFMA16(am[fi], bv, acc[fi][fj]);
        }
    }
    #pragma unroll
    for (int fi = 0; fi < 4; fi++)
    #pragma unroll
    for (int fj = 0; fj < 7; fj++) {
        int nn = w*112 + fj*16 + l15;
        #pragma unroll
        for (int r = 0; r < 4; r++) {
            int pp = p0 + fi*16 + l4*4 + r;
            float v = acc[fi][fj][r];
            size_t rowb = (size_t)bt*1024 + pp;
            if (nn < 64)       keyb[rowb*64 + nn] = (bf16_t)v;
            else if (nn == 64) msb[rowb] = v*v + 1.f;
            else if (nn < 129) qeb[rowb*64 + (nn-65)] = (bf16_t)(1.f/(1.f+expf(-v)));
            else if (nn < 385) f16b[rowb*256 + (nn-129)] = (bf16_t)v;
        }
    }
}

// ---------------- Qfeat: [qe*qk | qe | b_sq | zeros] bf16 ----------------
__global__ __launch_bounds__(512)
void k_qf(const bf16_t* __restrict__ keyb, const bf16_t* __restrict__ qeb,
          bf16_t* __restrict__ qfb)
{
    int bt = blockIdx.x;
    int p = blockIdx.y*8 + threadIdx.y;
    int c = threadIdx.x;
    size_t rowb = (size_t)bt*1024 + p;
    float qk = (float)keyb[rowb*64 + c];
    float qv = (float)qeb[rowb*64 + c];
    float bsq = qv*qk*qk;
    #pragma unroll
    for (int off = 32; off; off >>= 1) bsq += __shfl_xor(bsq, off);
    bf16_t* q = qfb + rowb*160;
    q[c]      = (bf16_t)(qv*qk);
    q[64 + c] = (bf16_t)qv;
    if (c == 0) q[128] = (bf16_t)bsq;
    if (c < 31) q[129 + c] = (bf16_t)0.f;
}

// ---------------- Kfeat rows for a memory slot ----------------
__global__ __launch_bounds__(512)
void k_kf(const bf16_t* __restrict__ keyb, const float* __restrict__ msb,
          bf16_t* __restrict__ kfb, int tm, int slot)
{
    int b = blockIdx.x;
    int p = blockIdx.y*8 + threadIdx.y;
    int c = threadIdx.x;
    size_t rowb = (size_t)(b*16 + tm)*1024 + p;
    float mk = (float)keyb[rowb*64 + c];
    float m  = msb[rowb];
    bf16_t* kr = kfb + ((size_t)b*3072 + slot*1024 + p)*160;
    kr[c]      = (bf16_t)( m*mk*0.25f);
    kr[64 + c] = (bf16_t)(-m*mk*mk*0.125f);
    if (c == 0) kr[128] = (bf16_t)(-m*0.125f);
    if (c < 31) kr[129 + c] = (bf16_t)0.f;
}

// ---------------- t=0 mask: aggregate + 16x16 avg-pool (coalesced) ----------------
__global__ __launch_bounds__(256)
void k_mask0(const float* __restrict__ im, float* __restrict__ wmask)
{
    int blk = blockIdx.x;
    int b = blk >> 5, i = blk & 31;
    int tid = threadIdx.x;
    int xq = tid & 127, yh = tid >> 7;
    const float* base = im + (size_t)b*262144 + (size_t)(i*16)*512;
    float s = 0.f;
    for (int yy = 0; yy < 8; yy++) {
        int y = yy*2 + yh;
        float4 v = *(const float4*)(base + (size_t)y*512 + xq*4);
        float e[4] = {v.x, v.y, v.z, v.w};
        #pragma unroll
        for (int u = 0; u < 4; u++) {
            float pc = fminf(fmaxf(e[u],      1e-7f), 1.f-1e-7f);
            float qc = fminf(fmaxf(1.f-e[u],  1e-7f), 1.f-1e-7f);
            s += pc*pc/(pc*pc + qc*qc);
        }
    }
    __shared__ float red[32];
    if (tid < 32) red[tid] = 0.f;
    __syncthreads();
    atomicAdd(&red[xq >> 2], s);
    __syncthreads();
    if (tid < 32) wmask[b*1024 + i*32 + tid] = red[tid]*(1.f/256.f);
}

// ---------------- value (MFMA): V = f16 @ Wv[0:256] + wmask*Wv[256] ----------------
__global__ __launch_bounds__(256)
void k_value(const bf16_t* __restrict__ f16b, const float* __restrict__ wmk,
             const bf16_t* __restrict__ WvT, const float* __restrict__ Wv,
             bf16_t* __restrict__ vb, int t, int slot)
{
    int b = blockIdx.z;
    int n0 = blockIdx.x*64, p0 = blockIdx.y*64;
    const int tid = threadIdx.x, lane = tid & 63, w = tid >> 6;
    const int wr = w >> 1, wc = w & 1, l15 = lane & 15, l4 = lane >> 4;
    const bf16_t* A = f16b + ((size_t)(b*16 + t)*1024 + p0)*256;
    f32x4 acc[2][2] = {};
    int ar = wr*32 + l15, bc = n0 + wc*32 + l15, koff = l4*8;
    #pragma unroll
    for (int ks = 0; ks < 8; ks++) {
        bf16x8 a0 = *(const bf16x8*)(A + (size_t)ar*256 + ks*32 + koff);
        bf16x8 a1 = *(const bf16x8*)(A + (size_t)(ar+16)*256 + ks*32 + koff);
        bf16x8 b0 = *(const bf16x8*)(WvT + (size_t)bc*256 + ks*32 + koff);
        bf16x8 b1 = *(const bf16x8*)(WvT + (size_t)(bc+16)*256 + ks*32 + koff);
        acc[0][0] = MFMA16(a0, b0, acc[0][0]);
        acc[0][1] = MFMA16(a0, b1, acc[0][1]);
        acc[1][0] = MFMA16(a1, b0, acc[1][0]);
        acc[1][1] = MFMA16(a1, b1, acc[1][1]);
    }
    #pragma unroll
    for (int fi = 0; fi < 2; fi++)
    #pragma unroll
    for (int fj = 0; fj < 2; fj++) {
        int nn = n0 + wc*32 + fj*16 + l15;
        float wvl = Wv[131072 + nn];
        #pragma unroll
        for (int r = 0; r < 4; r++) {
            int pp = p0 + wr*32 + fi*16 + l4*4 + r;
            float wm = wmk[b*1024 + pp];
            vb[((size_t)b*3072 + slot*1024 + pp)*512 + nn] = (bf16_t)(acc[fi][fj][r] + wm*wvl);
        }
    }
}

// ---------------- Vh^T (MFMA): vhT[c][n]; row 65 = 1.0 (denominator column) ----------------
__global__ __launch_bounds__(256)
void k_vh(const bf16_t* __restrict__ vb, const bf16_t* __restrict__ whvT,
          bf16_t* __restrict__ vhT, int slot)
{
    int b = blockIdx.y;
    int n0 = blockIdx.x*64;
    const int tid = threadIdx.x, lane = tid & 63, w = tid >> 6;
    const int wr = w >> 1, wc = w & 1, l15 = lane & 15, l4 = lane >> 4;
    const bf16_t* A = vb + ((size_t)b*3072 + slot*1024 + n0)*512;
    f32x4 acc[2][4] = {};
    int ar = wr*32 + l15, koff = l4*8;
    #pragma unroll 4
    for (int ks = 0; ks < 16; ks++) {
        bf16x8 a0 = *(const bf16x8*)(A + (size_t)ar*512 + ks*32 + koff);
        bf16x8 a1 = *(const bf16x8*)(A + (size_t)(ar+16)*512 + ks*32 + koff);
        #pragma unroll
        for (int fj = 0; fj < 4; fj++) {
            int cc = wc*64 + fj*16 + l15;
            bf16x8 bv = *(const bf16x8*)(whvT + (size_t)cc*512 + ks*32 + koff);
            acc[0][fj] = MFMA16(a0, bv, acc[0][fj]);
            acc[1][fj] = MFMA16(a1, bv, acc[1][fj]);
        }
    }
    #pragma unroll
    for (int fi = 0; fi < 2; fi++)
    #pragma unroll
    for (int fj = 0; fj < 4; fj++) {
        int cc = wc*64 + fj*16 + l15;
        #pragma unroll
        for (int r = 0; r < 4; r++) {
            int nn = n0 + wr*32 + fi*16 + l4*4 + r;
            float val = (cc < 65) ? acc[fi][fj][r] : (cc == 65 ? 1.f : 0.f);
            vhT[(size_t)b*393216 + (size_t)cc*3072 + slot*1024 + nn] = (bf16_t)val;
        }
    }
}

// ---------------- pre16 (MFMA): f16 @ [Whd_lo|Wdec_lo] -> [p][65] ----------------
__global__ __launch_bounds__(256)
void k_pre16(const bf16_t* __restrict__ f16b, const bf16_t* __restrict__ whfT,
             bf16_t* __restrict__ p16b)
{
    int bt = blockIdx.y;
    int p0 = blockIdx.x*64;
    const int tid = threadIdx.x, lane = tid & 63, w = tid >> 6;
    const int wr = w >> 1, wc = w & 1, l15 = lane & 15, l4 = lane >> 4;
    const bf16_t* A = f16b + ((size_t)bt*1024 + p0)*256;
    f32x4 acc[2][4] = {};
    int ar = wr*32 + l15, koff = l4*8;
    #pragma unroll
    for (int ks = 0; ks < 8; ks++) {
        bf16x8 a0 = *(const bf16x8*)(A + (size_t)ar*256 + ks*32 + koff);
        bf16x8 a1 = *(const bf16x8*)(A + (size_t)(ar+16)*256 + ks*32 + koff);
        #pragma unroll
        for (int fj = 0; fj < 4; fj++) {
            int cc = wc*64 + fj*16 + l15;
            bf16x8 bv = *(const bf16x8*)(whfT + (size_t)cc*256 + ks*32 + koff);
            acc[0][fj] = MFMA16(a0, bv, acc[0][fj]);
            acc[1][fj] = MFMA16(a1, bv, acc[1][fj]);
        }
    }
    #pragma unroll
    for (int fi = 0; fi < 2; fi++)
    #pragma unroll
    for (int fj = 0; fj < 4; fj++) {
        int cc = wc*64 + fj*16 + l15;
        if (cc < 65) {
            #pragma unroll
            for (int r = 0; r < 4; r++) {
                int pp = p0 + wr*32 + fi*16 + l4*4 + r;
                p16b[((size_t)bt*1024 + pp)*72 + cc] = (bf16_t)acc[fi][fj][r];
            }
        }
    }
}

// ---------------- split-N attention: exp(S)·Vh partials, NO max/sum needed ----------------
// sim <= ~0 algebraically (negative scaled distance), so exp never overflows.
// Denominator comes free via vhT ones-row (col 65). Slice = 256 keys.
// grid (16 ptile, 5 ts, 2b*ns), block 256 = 4 independent waves.
__global__ __launch_bounds__(256)
void k_att(const bf16_t* __restrict__ qfb, const bf16_t* __restrict__ kfb,
           const bf16_t* __restrict__ vhT, float* __restrict__ PVp, int t0)
{
    int b = blockIdx.z & 1, sl = blockIdx.z >> 1;
    int ts = blockIdx.y, t = t0 + ts, p0 = blockIdx.x*64;
    int n_base = sl*256;
    int tid = threadIdx.x, lane = tid & 63, w = tid >> 6;
    int l15 = lane & 15, l4 = lane >> 4;
    __shared__ __align__(16) bf16_t P_lds[4][16][72];

    const bf16_t* Q = qfb + ((size_t)(b*16 + t)*1024 + p0 + w*16 + l15)*160 + l4*8;
    bf16x8 aq[5];
    #pragma unroll
    for (int kc = 0; kc < 5; kc++) aq[kc] = *(const bf16x8*)(Q + kc*32);

    const bf16_t* K  = kfb + ((size_t)b*3072 + n_base)*160;
    const bf16_t* Vh = vhT + (size_t)b*393216 + n_base;
    f32x4 o[5] = {};

    for (int n0 = 0; n0 < 256; n0 += 64) {
        f32x4 s[4] = {};
        #pragma unroll
        for (int kc = 0; kc < 5; kc++) {
            #pragma unroll
            for (int nf = 0; nf < 4; nf++) {
                bf16x8 bk = *(const bf16x8*)(K + (size_t)(n0 + nf*16 + l15)*160 + kc*32 + l4*8);
                s[nf] = MFMA16(aq[kc], bk, s[nf]);
            }
        }
        #pragma unroll
        for (int nf = 0; nf < 4; nf++) {
            #pragma unroll
            for (int r = 0; r < 4; r++) {
                float pe = __expf(s[nf][r]);
                P_lds[w][l4*4 + r][nf*16 + l15] = (bf16_t)pe;
            }
        }
        #pragma unroll
        for (int kc2 = 0; kc2 < 2; kc2++) {
            bf16x8 ap = *(const bf16x8*)&P_lds[w][l15][kc2*32 + l4*8];
            #pragma unroll
            for (int cf = 0; cf < 5; cf++) {
                bf16x8 bv = *(const bf16x8*)(Vh + (size_t)(cf*16 + l15)*3072 + n0 + kc2*32 + l4*8);
                o[cf] = MFMA16(ap, bv, o[cf]);
            }
        }
    }
    float* O = PVp + (size_t)sl*PVSTR + ((size_t)((b*5 + ts)*1024) + p0 + w*16)*72;
    #pragma unroll
    for (int cf = 0; cf < 5; cf++) {
        int cc = cf*16 + l15;
        if (cc < 66) {
            #pragma unroll
            for (int r = 0; r < 4; r++)
                O[(size_t)(l4*4 + r)*72 + cc] = o[cf][r];
        }
    }
}

// ---------------- sequential 5-step chain; sums PV slices, divides by col65 ----------------
// grid (256, 2), block 256
__global__ __launch_bounds__(256)
void k_chain2(const bf16_t* __restrict__ p16b, const float* __restrict__ PVp,
              const float* __restrict__ whhbuf, float* __restrict__ hidden,
              float* __restrict__ wmk, float* __restrict__ mh, int t0, int ph, int ns)
{
    int b = blockIdx.y;
    int tid = threadIdx.x, lane = tid & 63, w = tid >> 6;
    int p = blockIdx.x*4 + w;
    __shared__ float whh_s[64][66];
    __shared__ float hid_s[4][64];
    for (int idx = tid; idx < 64*66; idx += 256) whh_s[idx/66][idx%66] = whhbuf[idx];
    float h = hidden[((size_t)b*1024 + p)*64 + lane];
    hid_s[w][lane] = h;
    __syncthreads();
    float wd = whh_s[lane][64];
    for (int ts = 0; ts < 5; ts++) {
        int t = t0 + ts;
        size_t r16 = ((size_t)(b*16 + t)*1024 + p)*72;
        size_t rpv = ((size_t)((b*5 + ts)*1024) + p)*72;
        float pvc = 0.f, pv64 = 0.f, pv65 = 0.f;
        for (int s2 = 0; s2 < ns; s2++) {
            const float* bp = PVp + (size_t)s2*PVSTR + rpv;
            pvc  += bp[lane];
            pv64 += bp[64];
            pv65 += bp[65];
        }
        float rinv  = 1.f/pv65;
        float pre   = (float)p16b[r16 + lane] + pvc*rinv;
        float fgpre = (float)p16b[r16 + 64]   + pv64*rinv;
        float s = pre;
        #pragma unroll 8
        for (int k = 0; k < 64; k++) s += hid_s[w][k]*whh_s[k][lane];
        float hl = tanhf(s);
        float fgs = hl*wd;
        #pragma unroll
        for (int off = 1; off < 64; off <<= 1) fgs += __shfl_xor(fgs, off);
        float fg = fgpre + fgs;
        float m = 1.f/(1.f+expf(-fg));
        size_t rmh = ((size_t)(b*15 + ph*5 + ts)*1024 + p)*66;
        mh[rmh + lane] = m*hl;
        if (lane == 0) mh[rmh + 64] = m;
        if (ts == 4 && lane == 0) wmk[b*1024 + p] = m;
        h = hl;
        __syncthreads();
        hid_s[w][lane] = h;
        __syncthreads();
    }
    hidden[((size_t)b*1024 + p)*64 + lane] = h;
}

// ---------------- hidden GEMM (f32 SIMT, small): tanh([V|hid?] @ Wh2) ----------------
__global__ __launch_bounds__(256)
void k_hid(const bf16_t* __restrict__ vb, const float* __restrict__ Wh2,
           float* __restrict__ hidden, int vslot, int has_h)
{
    int b = blockIdx.z; int p0 = blockIdx.y*64;
    int tid = threadIdx.x, tx = tid & 15, ty = tid >> 4;
    __shared__ float As[16][68], Bs[16][68];
    float acc[4][4] = {};
    const bf16_t* A = vb + ((size_t)b*3072 + vslot*1024)*512;
    const float* Hh = hidden + (size_t)b*1024*64;
    int KK = has_h ? 576 : 512;
    const int kk = tid & 15, rr = tid >> 4, colB = tid & 63, kB = tid >> 6;
    for (int k0 = 0; k0 < KK; k0 += 16) {
        #pragma unroll
        for (int s = 0; s < 4; s++) {
            int row = rr + s*16, p = p0 + row, k = k0 + kk;
            As[kk][row] = (k < 512) ? (float)A[(size_t)p*512 + k] : Hh[(size_t)p*64 + (k-512)];
        }
        #pragma unroll
        for (int s = 0; s < 4; s++) { int kb2 = kB + s*4; Bs[kb2][colB] = Wh2[(size_t)(k0+kb2)*64 + colB]; }
        __syncthreads();
        #pragma unroll
        for (int q = 0; q < 16; q++) {
            float4 av = *(const float4*)&As[q][ty*4];
            float4 bv = *(const float4*)&Bs[q][tx*4];
            float a_[4] = {av.x,av.y,av.z,av.w};
            float b_[4] = {bv.x,bv.y,bv.z,bv.w};
            #pragma unroll
            for (int i = 0; i < 4; i++)
                #pragma unroll
                for (int j = 0; j < 4; j++)
                    acc[i][j] = fmaf(a_[i], b_[j], acc[i][j]);
        }
        __syncthreads();
    }
    #pragma unroll
    for (int i = 0; i < 4; i++) {
        int p = p0 + ty*4 + i;
        #pragma unroll
        for (int j = 0; j < 4; j++)
            hidden[(size_t)(b*1024 + p)*64 + tx*4 + j] = tanhf(acc[i][j]);
    }
}

// ---------------- feat t=0: mean over spatial of key ----------------
__global__ void k_feat0(const bf16_t* __restrict__ keyb, float* __restrict__ out)
{
    int b = blockIdx.x, c = threadIdx.x;
    const bf16_t* kb = keyb + (size_t)(b*16)*1024*64;
    float s = 0.f;
    for (int p = 0; p < 1024; p++) s += (float)kb[(size_t)p*64 + c];
    out[(size_t)(b*16)*64 + c] = s*(1.f/1024.f);
}

// ---------------- feats t=1..15: weighted mean reduce (parallel) ----------------
__global__ __launch_bounds__(256)
void k_feats(const float* __restrict__ mh, float* __restrict__ out)
{
    int slot = blockIdx.x, b = blockIdx.y, t = slot + 1;
    int tid = threadIdx.x, c = tid & 63, g = tid >> 6;
    const float* base = mh + (size_t)(b*15 + slot)*1024*66;
    float s = 0.f, sm = 0.f;
    for (int p = g; p < 1024; p += 4) {
        s += base[(size_t)p*66 + c];
        if (c == 0) sm += base[(size_t)p*66 + 64];
    }
    __shared__ float red[4][64];
    __shared__ float redm[4];
    red[g][c] = s;
    if (c == 0) redm[g] = sm;
    __syncthreads();
    if (g == 0) {
        float tot  = red[0][c] + red[1][c] + red[2][c] + red[3][c];
        float totm = redm[0] + redm[1] + redm[2] + redm[3];
        out[(size_t)(b*16 + t)*64 + c] = tot / fmaxf(totm, 1e-6f);
    }
}

// ---------------- host launcher ----------------
extern "C" void kernel_launch(void* const* d_in, const int* in_sizes, int n_in,
                              void* d_out, int out_size, void* d_ws, size_t ws_size,
                              hipStream_t stream)
{
    (void)in_sizes; (void)n_in; (void)out_size;
    if (ws_size < ws_need*sizeof(float)) return;
    const float* frames = (const float*)d_in[0];
    const float* imask  = (const float*)d_in[1];
    const float* Wk   = (const float*)d_in[3];
    const float* Wsh  = (const float*)d_in[4];
    const float* Wse  = (const float*)d_in[5];
    const float* Wf   = (const float*)d_in[6];
    const float* Wv   = (const float*)d_in[7];
    const float* Wh2  = (const float*)d_in[8];
    const float* Whd  = (const float*)d_in[9];
    const float* Wdec = (const float*)d_in[10];
    float* out = (float*)d_out;
    float* ws  = (float*)d_ws;

    bf16_t* wcatT = (bf16_t*)(ws + o_wcatT);
    bf16_t* whfT  = (bf16_t*)(ws + o_whfT);
    bf16_t* whvT  = (bf16_t*)(ws + o_whvT);
    bf16_t* WvT   = (bf16_t*)(ws + o_WvT);
    float*  whh   = ws + o_whh;
    bf16_t* keyb  = (bf16_t*)(ws + o_keyb);
    float*  msb   = ws + o_ms;
    bf16_t* qeb   = (bf16_t*)(ws + o_qeb);
    bf16_t* f16b  = (bf16_t*)(ws + o_f16b);
    bf16_t* qfb   = (bf16_t*)(ws + o_qfb);
    bf16_t* kfb   = (bf16_t*)(ws + o_kfb);
    bf16_t* vb    = (bf16_t*)(ws + o_vb);
    bf16_t* vhT   = (bf16_t*)(ws + o_vhT);
    float*  PVp   = ws + o_pv;
    bf16_t* p16b  = (bf16_t*)(ws + o_p16);
    float*  mh    = ws + o_mh;
    float*  hid   = ws + o_hid;
    float*  wmk   = ws + o_wmk;

    k_init<<<2257, 256, 0, stream>>>(Wk, Wsh, Wse, Wf, Wv, Whd, Wdec,
                                     wcatT, whfT, whvT, WvT, whh);
    k_proj<<<dim3(16,32), 256, 0, stream>>>(frames, wcatT, keyb, msb, qeb, f16b);
    k_qf<<<dim3(32,128), dim3(64,8), 0, stream>>>(keyb, qeb, qfb);
    k_mask0<<<64, 256, 0, stream>>>(imask, wmk);
    k_kf<<<dim3(2,128), dim3(64,8), 0, stream>>>(keyb, msb, kfb, 0, 0);
    k_value<<<dim3(8,16,2), 256, 0, stream>>>(f16b, wmk, WvT, Wv, vb, 0, 0);
    k_vh<<<dim3(16,2), 256, 0, stream>>>(vb, whvT, vhT, 0);
    k_hid<<<dim3(1,16,2), 256, 0, stream>>>(vb, Wh2, hid, 0, 0);
    k_feat0<<<2, 64, 0, stream>>>(keyb, out);
    k_pre16<<<dim3(16,32), 256, 0, stream>>>(f16b, whfT, p16b);

    for (int ph = 0; ph < 3; ph++) {
        int t0 = 1 + ph*5;
        int ns = (ph + 1)*4;            // N/256 slices: 4, 8, 12
        k_att<<<dim3(16,5,2*ns), 256, 0, stream>>>(qfb, kfb, vhT, PVp, t0);
        k_chain2<<<dim3(256,2), 256, 0, stream>>>(p16b, PVp, whh, hid, wmk, mh, t0, ph, ns);
        if (ph < 2) {
            int tm = t0 + 4, slot = ph + 1;
            k_kf<<<dim3(2,128), dim3(64,8), 0, stream>>>(keyb, msb, kfb, tm, slot);
            k_value<<<dim3(8,16,2), 256, 0, stream>>>(f16b, wmk, WvT, Wv, vb, tm, slot);
            k_vh<<<dim3(16,2), 256, 0, stream>>>(vb, whvT, vhT, slot);
            if (ph == 1) k_hid<<<dim3(1,16,2), 256, 0, stream>>>(vb, Wh2, hid, 2, 1);
        }
    }
    k_feats<<<dim3(15,2), 256, 0, stream>>>(mh, out);
}

// Round 6
// 557.581 us; speedup vs baseline: 1.8924x; 1.1432x over previous
//
#include <hip/hip_runtime.h>
#include <cstdint>

typedef __bf16 bf16_t;
typedef __attribute__((ext_vector_type(8))) __bf16 bf16x8;
typedef __attribute__((ext_vector_type(4))) __bf16 bf16x4;
typedef __attribute__((ext_vector_type(4))) float f32x4;

#define MFMA16(a,b,c) __builtin_amdgcn_mfma_f32_16x16x32_bf16((a),(b),(c),0,0,0)

// ---------------- workspace offsets (float units) ----------------
constexpr size_t PVSTR   = (size_t)2*5*1024*72;  // one N-slice of PV partials
constexpr size_t o_wcatT = 0;                    // bf16 [448][768]
constexpr size_t o_whfT  = o_wcatT + 172032;     // bf16 [128][256]
constexpr size_t o_wvhT  = o_whfT  + 16384;      // bf16 [80][256]  fused Wv@Whv (transposed)
constexpr size_t o_wvh1  = o_wvhT  + 10240;      // f32  [65]  (mask-row of fused weight)
constexpr size_t o_WvT   = o_wvh1  + 80;         // bf16 [512][256]
constexpr size_t o_whh   = o_WvT   + 65536;      // f32  [64][66]
constexpr size_t o_wh2T  = o_whh   + 4224;       // bf16 [64][576]
constexpr size_t o_keyb  = o_wh2T  + 18432;      // bf16 [B*T*1024][64]
constexpr size_t o_ms    = o_keyb  + 1048576;    // f32  [B*T*1024]
constexpr size_t o_qeb   = o_ms    + 32768;      // bf16 [B*T*1024][64]
constexpr size_t o_f16b  = o_qeb   + 1048576;    // bf16 [B*T*1024][256]
constexpr size_t o_qfb   = o_f16b  + 4194304;    // bf16 [B*T*1024][160]
constexpr size_t o_kfb   = o_qfb   + 2621440;    // bf16 [B*3072][160]
constexpr size_t o_vb    = o_kfb   + 491520;     // bf16 [B*3072][512] (slots 0,2 used)
constexpr size_t o_vhT   = o_vb    + 1572864;    // bf16 [B][128][3072] (row65 = ones)
constexpr size_t o_pv    = o_vhT   + 393216;     // f32  [12 slices][B][5][1024][72]
constexpr size_t o_p16   = o_pv    + 12*PVSTR;   // bf16 [B*T*1024][72]
constexpr size_t o_mh    = o_p16   + 1179648;    // f32  [B][15][1024][66]
constexpr size_t o_hid   = o_mh    + 2027520;    // f32  [B][1024][64]
constexpr size_t o_wmk   = o_hid   + 131072;     // f32  [B][1024]
constexpr size_t ws_need = o_wmk   + 2048;

// ---------------- init: transposed bf16 weight panels + zero out[t=0] ----------------
__global__ __launch_bounds__(256)
void k_init(const float* __restrict__ Wk, const float* __restrict__ Wsh,
            const float* __restrict__ Wse, const float* __restrict__ Wf,
            const float* __restrict__ Wv, const float* __restrict__ Wh2,
            const float* __restrict__ Whd, const float* __restrict__ Wdec,
            bf16_t* __restrict__ wcatT, bf16_t* __restrict__ whfT,
            bf16_t* __restrict__ WvT, float* __restrict__ whh,
            bf16_t* __restrict__ wh2T, float* __restrict__ out)
{
    int idx = blockIdx.x*256 + threadIdx.x;
    if (idx < 344064) {                       // wcatT[n][k] n<448 k<768
        int n = idx/768, k = idx%768;
        float v = 0.f;
        if (n < 64)       v = Wk[k*64+n];
        else if (n == 64) v = Wsh[k];
        else if (n < 129) v = Wse[k*64+(n-65)];
        else if (n < 385) v = Wf[k*256+(n-129)];
        wcatT[idx] = (bf16_t)v;
        return;
    }
    idx -= 344064;
    if (idx < 32768) {                        // whfT[c][k] c<128 k<256
        int c = idx/256, k = idx%256;
        float v = 0.f;
        if (c < 64) v = Whd[k*64+c]; else if (c == 64) v = Wdec[k];
        whfT[idx] = (bf16_t)v;
        return;
    }
    idx -= 32768;
    if (idx < 131072) {                       // WvT[n][k] n<512 k<256
        int n = idx/256, k = idx%256;
        WvT[idx] = (bf16_t)Wv[k*512+n];
        return;
    }
    idx -= 131072;
    if (idx < 4224) {                         // whh[k][c] (stride 66), c<65 real
        int k = idx/66, c = idx%66;
        float v = 0.f;
        if (c < 64) v = Whd[(768+k)*64+c]; else if (c == 64) v = Wdec[768+k];
        whh[idx] = v;
        return;
    }
    idx -= 4224;
    if (idx < 36864) {                        // wh2T[c][k] c<64 k<576
        int c = idx/576, k = idx%576;
        wh2T[idx] = (bf16_t)Wh2[k*64+c];
        return;
    }
    idx -= 36864;
    if (idx < 128) {                          // zero out[t=0] (feat0 atomics)
        int b = idx>>6, c = idx&63;
        out[(size_t)b*1024 + c] = 0.f;
    }
}

// ---------------- fused weight: Wvh[k][c] = Wv[k]@whv(:,c); wvh1 = Wv[256]@whv ----------------
// grid 81, block 256. whv(j,c) = Whd[(256+j)*64+c] (c<64) | Wdec[256+j] (c==64)
__global__ __launch_bounds__(256)
void k_wfuse(const float* __restrict__ Wv, const float* __restrict__ Whd,
             const float* __restrict__ Wdec, bf16_t* __restrict__ wvhT,
             float* __restrict__ wvh1)
{
    int idx = blockIdx.x*256 + threadIdx.x;
    if (idx < 20480) {
        int k = idx / 80, c = idx % 80;
        float s = 0.f;
        if (c < 65) {
            for (int j = 0; j < 512; j++) {
                float hv = (c < 64) ? Whd[(256+j)*64 + c] : Wdec[256 + j];
                s = fmaf(Wv[k*512 + j], hv, s);
            }
        }
        wvhT[(size_t)c*256 + k] = (bf16_t)s;
        return;
    }
    idx -= 20480;
    if (idx < 65) {
        int c = idx;
        float s = 0.f;
        for (int j = 0; j < 512; j++) {
            float hv = (c < 64) ? Whd[(256+j)*64 + c] : Wdec[256 + j];
            s = fmaf(Wv[256*512 + j], hv, s);
        }
        wvh1[c] = s;
    }
}

// ---------------- projection GEMM v2: 32-row tiles, dbuf LDS, 1 barrier/chunk ----------------
// grid (32 ptile, 32 bt), block 256 (4 waves). tile 32 rows x 448 cols, 24 K-chunks of 32.
__global__ __launch_bounds__(256)
void k_proj(const float* __restrict__ frames, const bf16_t* __restrict__ wcatT,
            bf16_t* __restrict__ keyb, float* __restrict__ msb,
            bf16_t* __restrict__ qeb, bf16_t* __restrict__ f16b)
{
    const int bx = blockIdx.x, bt = blockIdx.y;
    const int p0 = bx*32;
    const int tid = threadIdx.x, lane = tid & 63, w = tid >> 6;
    const int l15 = lane & 15, l4 = lane >> 4;
    __shared__ __align__(16) bf16_t Al[2][32][40];
    f32x4 acc[2][7] = {};
    const float* fb = frames + (size_t)bt*786432;
    // loader: thread -> (r = image-row parity, x4 = 4 consecutive floats of 512-row)
    const int r = tid >> 7, xx = tid & 127, x4 = xx*4;
    const int j = xx >> 2, pj = (xx & 3)*4;     // LDS row j (position), col r*16+pj
    const int ybase = bx*16 + r;

    #define PROJ_ADDR(kc) ((const float4*)(fb + (size_t)((kc)>>3)*262144 + \
        (size_t)(ybase + (((kc)*32 & 255) >> 4))*512 + x4))
    #define PROJ_STORE(buf, v) { bf16x4 pk; pk[0]=(bf16_t)(v).x; pk[1]=(bf16_t)(v).y; \
        pk[2]=(bf16_t)(v).z; pk[3]=(bf16_t)(v).w; *(bf16x4*)&Al[buf][j][r*16+pj] = pk; }
    #define PROJ_MFMA(buf, kc) { \
        bf16x8 a0 = *(const bf16x8*)&Al[buf][l15][l4*8]; \
        bf16x8 a1 = *(const bf16x8*)&Al[buf][16+l15][l4*8]; \
        _Pragma("unroll") \
        for (int fj = 0; fj < 7; fj++) { \
            int n = w*112 + fj*16 + l15; \
            bf16x8 bv = *(const bf16x8*)(wcatT + (size_t)n*768 + (kc)*32 + l4*8); \
            acc[0][fj] = MFMA16(a0, bv, acc[0][fj]); \
            acc[1][fj] = MFMA16(a1, bv, acc[1][fj]); \
        } }

    float4 nx0 = *PROJ_ADDR(0);
    float4 nx1 = *PROJ_ADDR(1);
    PROJ_STORE(0, nx0);
    for (int kc = 0; kc < 24; kc += 2) {
        __syncthreads();                       // buf0 (chunk kc) ready
        if (kc+2 < 24) nx0 = *PROJ_ADDR(kc+2);
        PROJ_MFMA(0, kc);
        PROJ_STORE(1, nx1);                    // buf1 <- chunk kc+1
        __syncthreads();
        if (kc+3 < 24) nx1 = *PROJ_ADDR(kc+3);
        PROJ_MFMA(1, kc+1);
        if (kc+2 < 24) PROJ_STORE(0, nx0);     // buf0 <- chunk kc+2
    }
    #undef PROJ_ADDR
    #undef PROJ_STORE
    #undef PROJ_MFMA

    #pragma unroll
    for (int fi = 0; fi < 2; fi++)
    #pragma unroll
    for (int fj = 0; fj < 7; fj++) {
        int nn = w*112 + fj*16 + l15;
        #pragma unroll
        for (int rr = 0; rr < 4; rr++) {
            int pp = p0 + fi*16 + l4*4 + rr;
            float v = acc[fi][fj][rr];
            size_t rowb = (size_t)bt*1024 + pp;
            if (nn < 64)       keyb[rowb*64 + nn] = (bf16_t)v;
            else if (nn == 64) msb[rowb] = v*v + 1.f;
            else if (nn < 129) qeb[rowb*64 + (nn-65)] = (bf16_t)(1.f/(1.f+expf(-v)));
            else if (nn < 385) f16b[rowb*256 + (nn-129)] = (bf16_t)v;
        }
    }
}

// ---------------- Qfeat: [qe*qk | qe | b_sq | zeros] bf16 ----------------
__global__ __launch_bounds__(512)
void k_qf(const bf16_t* __restrict__ keyb, const bf16_t* __restrict__ qeb,
          bf16_t* __restrict__ qfb)
{
    int bt = blockIdx.x;
    int p = blockIdx.y*8 + threadIdx.y;
    int c = threadIdx.x;
    size_t rowb = (size_t)bt*1024 + p;
    float qk = (float)keyb[rowb*64 + c];
    float qv = (float)qeb[rowb*64 + c];
    float bsq = qv*qk*qk;
    #pragma unroll
    for (int off = 32; off; off >>= 1) bsq += __shfl_xor(bsq, off);
    bf16_t* q = qfb + rowb*160;
    q[c]      = (bf16_t)(qv*qk);
    q[64 + c] = (bf16_t)qv;
    if (c == 0) q[128] = (bf16_t)bsq;
    if (c < 31) q[129 + c] = (bf16_t)0.f;
}

// ---------------- t=0 mask: aggregate + 16x16 avg-pool (coalesced) ----------------
__global__ __launch_bounds__(256)
void k_mask0(const float* __restrict__ im, float* __restrict__ wmask)
{
    int blk = blockIdx.x;
    int b = blk >> 5, i = blk & 31;
    int tid = threadIdx.x;
    int xq = tid & 127, yh = tid >> 7;
    const float* base = im + (size_t)b*262144 + (size_t)(i*16)*512;
    float s = 0.f;
    for (int yy = 0; yy < 8; yy++) {
        int y = yy*2 + yh;
        float4 v = *(const float4*)(base + (size_t)y*512 + xq*4);
        float e[4] = {v.x, v.y, v.z, v.w};
        #pragma unroll
        for (int u = 0; u < 4; u++) {
            float pc = fminf(fmaxf(e[u],      1e-7f), 1.f-1e-7f);
            float qc = fminf(fmaxf(1.f-e[u],  1e-7f), 1.f-1e-7f);
            s += pc*pc/(pc*pc + qc*qc);
        }
    }
    __shared__ float red[32];
    if (tid < 32) red[tid] = 0.f;
    __syncthreads();
    atomicAdd(&red[xq >> 2], s);
    __syncthreads();
    if (tid < 32) wmask[b*1024 + i*32 + tid] = red[tid]*(1.f/256.f);
}

// ---------------- per-slot prep: kf rows + vhT GEMM (from f16 + fused weight) ----------------
// grid (16, 2), block 256 (4 waves). vhT[c][n] = f16@Wvh + wmask*wvh1; row65=1.
__global__ __launch_bounds__(256)
void k_prep(const bf16_t* __restrict__ f16b, const bf16_t* __restrict__ keyb,
            const float* __restrict__ msb, const float* __restrict__ wmk,
            const bf16_t* __restrict__ wvhT, const float* __restrict__ wvh1,
            bf16_t* __restrict__ kfb, bf16_t* __restrict__ vhT, int tm, int slot)
{
    int b = blockIdx.y, n0 = blockIdx.x*64;
    int tid = threadIdx.x, lane = tid & 63, w = tid >> 6;
    // ---- kf fill (independent of GEMM) ----
    {
        int row = n0 + (tid >> 2), q = tid & 3;
        size_t rowb = (size_t)(b*16 + tm)*1024 + row;
        float m = msb[rowb];
        bf16_t* kr = kfb + ((size_t)b*3072 + slot*1024 + row)*160;
        bf16x8 k0v = *(const bf16x8*)(keyb + rowb*64 + q*16);
        bf16x8 k1v = *(const bf16x8*)(keyb + rowb*64 + q*16 + 8);
        bf16x8 o0, o1, s0, s1;
        #pragma unroll
        for (int u = 0; u < 8; u++) {
            float mk0 = (float)k0v[u], mk1 = (float)k1v[u];
            o0[u] = (bf16_t)( m*mk0*0.25f);       o1[u] = (bf16_t)( m*mk1*0.25f);
            s0[u] = (bf16_t)(-m*mk0*mk0*0.125f);  s1[u] = (bf16_t)(-m*mk1*mk1*0.125f);
        }
        *(bf16x8*)(kr + q*16)      = o0;  *(bf16x8*)(kr + q*16 + 8)      = o1;
        *(bf16x8*)(kr + 64 + q*16) = s0;  *(bf16x8*)(kr + 64 + q*16 + 8) = s1;
        if (q == 0) kr[128] = (bf16_t)(-m*0.125f);
        else if (q == 1) { for (int u = 0; u < 15; u++) kr[129+u] = (bf16_t)0.f; }
        else if (q == 2) { for (int u = 0; u < 16; u++) kr[144+u] = (bf16_t)0.f; }
    }
    // ---- vh GEMM: 64 n-rows x 80 c, K=256 ----
    int l15 = lane & 15, l4 = lane >> 4;
    const bf16_t* A = f16b + ((size_t)(b*16 + tm)*1024 + n0 + w*16 + l15)*256;
    f32x4 acc[5] = {};
    #pragma unroll
    for (int ks = 0; ks < 8; ks++) {
        bf16x8 a0 = *(const bf16x8*)(A + ks*32 + l4*8);
        #pragma unroll
        for (int cf = 0; cf < 5; cf++) {
            bf16x8 bv = *(const bf16x8*)(wvhT + (size_t)(cf*16 + l15)*256 + ks*32 + l4*8);
            acc[cf] = MFMA16(a0, bv, acc[cf]);
        }
    }
    #pragma unroll
    for (int cf = 0; cf < 5; cf++) {
        int cc = cf*16 + l15;
        float w1 = (cc < 65) ? wvh1[cc] : 0.f;
        #pragma unroll
        for (int rr = 0; rr < 4; rr++) {
            int p = n0 + w*16 + l4*4 + rr;
            float val;
            if (cc < 65)      val = acc[cf][rr] + wmk[b*1024 + p]*w1;
            else              val = (cc == 65) ? 1.f : 0.f;
            vhT[(size_t)b*393216 + (size_t)cc*3072 + slot*1024 + p] = (bf16_t)val;
        }
    }
}

// ---------------- value (MFMA): V = f16 @ Wv[0:256] + wmask*Wv[256] (slots 0,2) ----------------
__global__ __launch_bounds__(256)
void k_value(const bf16_t* __restrict__ f16b, const float* __restrict__ wmk,
             const bf16_t* __restrict__ WvT, const float* __restrict__ Wv,
             bf16_t* __restrict__ vb, int t, int slot)
{
    int b = blockIdx.z;
    int n0 = blockIdx.x*64, p0 = blockIdx.y*64;
    const int tid = threadIdx.x, lane = tid & 63, w = tid >> 6;
    const int wr = w >> 1, wc = w & 1, l15 = lane & 15, l4 = lane >> 4;
    const bf16_t* A = f16b + ((size_t)(b*16 + t)*1024 + p0)*256;
    f32x4 acc[2][2] = {};
    int ar = wr*32 + l15, bc = n0 + wc*32 + l15, koff = l4*8;
    #pragma unroll
    for (int ks = 0; ks < 8; ks++) {
        bf16x8 a0 = *(const bf16x8*)(A + (size_t)ar*256 + ks*32 + koff);
        bf16x8 a1 = *(const bf16x8*)(A + (size_t)(ar+16)*256 + ks*32 + koff);
        bf16x8 b0 = *(const bf16x8*)(WvT + (size_t)bc*256 + ks*32 + koff);
        bf16x8 b1 = *(const bf16x8*)(WvT + (size_t)(bc+16)*256 + ks*32 + koff);
        acc[0][0] = MFMA16(a0, b0, acc[0][0]);
        acc[0][1] = MFMA16(a0, b1, acc[0][1]);
        acc[1][0] = MFMA16(a1, b0, acc[1][0]);
        acc[1][1] = MFMA16(a1, b1, acc[1][1]);
    }
    #pragma unroll
    for (int fi = 0; fi < 2; fi++)
    #pragma unroll
    for (int fj = 0; fj < 2; fj++) {
        int nn = n0 + wc*32 + fj*16 + l15;
        float wvl = Wv[131072 + nn];
        #pragma unroll
        for (int rr = 0; rr < 4; rr++) {
            int pp = p0 + wr*32 + fi*16 + l4*4 + rr;
            float wm = wmk[b*1024 + pp];
            vb[((size_t)b*3072 + slot*1024 + pp)*512 + nn] = (bf16_t)(acc[fi][fj][rr] + wm*wvl);
        }
    }
}

// ---------------- pre16 (MFMA): f16 @ [Whd_lo|Wdec_lo] -> [p][65] ----------------
__global__ __launch_bounds__(256)
void k_pre16(const bf16_t* __restrict__ f16b, const bf16_t* __restrict__ whfT,
             bf16_t* __restrict__ p16b)
{
    int bt = blockIdx.y;
    int p0 = blockIdx.x*64;
    const int tid = threadIdx.x, lane = tid & 63, w = tid >> 6;
    const int wr = w >> 1, wc = w & 1, l15 = lane & 15, l4 = lane >> 4;
    const bf16_t* A = f16b + ((size_t)bt*1024 + p0)*256;
    f32x4 acc[2][4] = {};
    int ar = wr*32 + l15, koff = l4*8;
    #pragma unroll
    for (int ks = 0; ks < 8; ks++) {
        bf16x8 a0 = *(const bf16x8*)(A + (size_t)ar*256 + ks*32 + koff);
        bf16x8 a1 = *(const bf16x8*)(A + (size_t)(ar+16)*256 + ks*32 + koff);
        #pragma unroll
        for (int fj = 0; fj < 4; fj++) {
            int cc = wc*64 + fj*16 + l15;
            bf16x8 bv = *(const bf16x8*)(whfT + (size_t)cc*256 + ks*32 + koff);
            acc[0][fj] = MFMA16(a0, bv, acc[0][fj]);
            acc[1][fj] = MFMA16(a1, bv, acc[1][fj]);
        }
    }
    #pragma unroll
    for (int fi = 0; fi < 2; fi++)
    #pragma unroll
    for (int fj = 0; fj < 4; fj++) {
        int cc = wc*64 + fj*16 + l15;
        if (cc < 65) {
            #pragma unroll
            for (int rr = 0; rr < 4; rr++) {
                int pp = p0 + wr*32 + fi*16 + l4*4 + rr;
                p16b[((size_t)bt*1024 + pp)*72 + cc] = (bf16_t)acc[fi][fj][rr];
            }
        }
    }
}

// ---------------- split-N attention: exp(S)·Vh partials (sim<=0, no max/sum) ----------------
__global__ __launch_bounds__(256)
void k_att(const bf16_t* __restrict__ qfb, const bf16_t* __restrict__ kfb,
           const bf16_t* __restrict__ vhT, float* __restrict__ PVp, int t0)
{
    int b = blockIdx.z & 1, sl = blockIdx.z >> 1;
    int ts = blockIdx.y, t = t0 + ts, p0 = blockIdx.x*64;
    int n_base = sl*256;
    int tid = threadIdx.x, lane = tid & 63, w = tid >> 6;
    int l15 = lane & 15, l4 = lane >> 4;
    __shared__ __align__(16) bf16_t P_lds[4][16][72];

    const bf16_t* Q = qfb + ((size_t)(b*16 + t)*1024 + p0 + w*16 + l15)*160 + l4*8;
    bf16x8 aq[5];
    #pragma unroll
    for (int kc = 0; kc < 5; kc++) aq[kc] = *(const bf16x8*)(Q + kc*32);

    const bf16_t* K  = kfb + ((size_t)b*3072 + n_base)*160;
    const bf16_t* Vh = vhT + (size_t)b*393216 + n_base;
    f32x4 o[5] = {};

    for (int n0 = 0; n0 < 256; n0 += 64) {
        f32x4 s[4] = {};
        #pragma unroll
        for (int kc = 0; kc < 5; kc++) {
            #pragma unroll
            for (int nf = 0; nf < 4; nf++) {
                bf16x8 bk = *(const bf16x8*)(K + (size_t)(n0 + nf*16 + l15)*160 + kc*32 + l4*8);
                s[nf] = MFMA16(aq[kc], bk, s[nf]);
            }
        }
        #pragma unroll
        for (int nf = 0; nf < 4; nf++) {
            #pragma unroll
            for (int rr = 0; rr < 4; rr++) {
                float pe = __expf(s[nf][rr]);
                P_lds[w][l4*4 + rr][nf*16 + l15] = (bf16_t)pe;
            }
        }
        #pragma unroll
        for (int kc2 = 0; kc2 < 2; kc2++) {
            bf16x8 ap = *(const bf16x8*)&P_lds[w][l15][kc2*32 + l4*8];
            #pragma unroll
            for (int cf = 0; cf < 5; cf++) {
                bf16x8 bv = *(const bf16x8*)(Vh + (size_t)(cf*16 + l15)*3072 + n0 + kc2*32 + l4*8);
                o[cf] = MFMA16(ap, bv, o[cf]);
            }
        }
    }
    float* O = PVp + (size_t)sl*PVSTR + ((size_t)((b*5 + ts)*1024) + p0 + w*16)*72;
    #pragma unroll
    for (int cf = 0; cf < 5; cf++) {
        int cc = cf*16 + l15;
        if (cc < 66) {
            #pragma unroll
            for (int rr = 0; rr < 4; rr++)
                O[(size_t)(l4*4 + rr)*72 + cc] = o[cf][rr];
        }
    }
}

// ---------------- sequential 5-step chain; sums PV slices, divides by col65 ----------------
__global__ __launch_bounds__(256)
void k_chain2(const bf16_t* __restrict__ p16b, const float* __restrict__ PVp,
              const float* __restrict__ whhbuf, float* __restrict__ hidden,
              float* __restrict__ wmk, float* __restrict__ mh, int t0, int ph, int ns)
{
    int b = blockIdx.y;
    int tid = threadIdx.x, lane = tid & 63, w = tid >> 6;
    int p = blockIdx.x*4 + w;
    __shared__ float whh_s[64][66];
    __shared__ float hid_s[4][64];
    for (int idx = tid; idx < 64*66; idx += 256) whh_s[idx/66][idx%66] = whhbuf[idx];
    float h = hidden[((size_t)b*1024 + p)*64 + lane];
    hid_s[w][lane] = h;
    __syncthreads();
    float wd = whh_s[lane][64];
    for (int ts = 0; ts < 5; ts++) {
        int t = t0 + ts;
        size_t r16 = ((size_t)(b*16 + t)*1024 + p)*72;
        size_t rpv = ((size_t)((b*5 + ts)*1024) + p)*72;
        float pvc = 0.f, pv64 = 0.f, pv65 = 0.f;
        for (int s2 = 0; s2 < ns; s2++) {
            const float* bp = PVp + (size_t)s2*PVSTR + rpv;
            pvc  += bp[lane];
            pv64 += bp[64];
            pv65 += bp[65];
        }
        float rinv  = 1.f/pv65;
        float pre   = (float)p16b[r16 + lane] + pvc*rinv;
        float fgpre = (float)p16b[r16 + 64]   + pv64*rinv;
        float s = pre;
        #pragma unroll 8
        for (int k = 0; k < 64; k++) s += hid_s[w][k]*whh_s[k][lane];
        float hl = tanhf(s);
        float fgs = hl*wd;
        #pragma unroll
        for (int off = 1; off < 64; off <<= 1) fgs += __shfl_xor(fgs, off);
        float fg = fgpre + fgs;
        float m = 1.f/(1.f+expf(-fg));
        size_t rmh = ((size_t)(b*15 + ph*5 + ts)*1024 + p)*66;
        mh[rmh + lane] = m*hl;
        if (lane == 0) mh[rmh + 64] = m;
        if (ts == 4 && lane == 0) wmk[b*1024 + p] = m;
        h = hl;
        __syncthreads();
        hid_s[w][lane] = h;
        __syncthreads();
    }
    hidden[((size_t)b*1024 + p)*64 + lane] = h;
}

// ---------------- hidden update (MFMA): tanh([V | hid?] @ Wh2) ----------------
// grid (16, 2), block 256 (4 waves); K = 512 (+64 when has_h)
__global__ __launch_bounds__(256)
void k_hidm(const bf16_t* __restrict__ vb, const bf16_t* __restrict__ wh2T,
            float* __restrict__ hidden, int vslot, int has_h)
{
    int b = blockIdx.y, p0 = blockIdx.x*64;
    int tid = threadIdx.x, lane = tid & 63, w = tid >> 6;
    int l15 = lane & 15, l4 = lane >> 4;
    int arow = p0 + w*16 + l15;
    const bf16_t* A = vb + ((size_t)b*3072 + vslot*1024 + arow)*512;
    const float* Hp = hidden + ((size_t)b*1024 + arow)*64;
    f32x4 acc[4] = {};
    int kiters = has_h ? 18 : 16;
    for (int ks = 0; ks < kiters; ks++) {
        bf16x8 a0;
        if (ks < 16) a0 = *(const bf16x8*)(A + ks*32 + l4*8);
        else {
            int ko = (ks-16)*32 + l4*8;
            float4 h0 = *(const float4*)(Hp + ko);
            float4 h1 = *(const float4*)(Hp + ko + 4);
            a0[0]=(bf16_t)h0.x; a0[1]=(bf16_t)h0.y; a0[2]=(bf16_t)h0.z; a0[3]=(bf16_t)h0.w;
            a0[4]=(bf16_t)h1.x; a0[5]=(bf16_t)h1.y; a0[6]=(bf16_t)h1.z; a0[7]=(bf16_t)h1.w;
        }
        #pragma unroll
        for (int cf = 0; cf < 4; cf++) {
            bf16x8 bv = *(const bf16x8*)(wh2T + (size_t)(cf*16 + l15)*576 + ks*32 + l4*8);
            acc[cf] = MFMA16(a0, bv, acc[cf]);
        }
    }
    #pragma unroll
    for (int cf = 0; cf < 4; cf++) {
        int cc = cf*16 + l15;
        #pragma unroll
        for (int rr = 0; rr < 4; rr++) {
            int p = p0 + w*16 + l4*4 + rr;
            hidden[((size_t)b*1024 + p)*64 + cc] = tanhf(acc[cf][rr]);
        }
    }
}

// ---------------- feat t=0: mean over spatial of key (parallel + atomic) ----------------
// grid (16, 2), block 256
__global__ __launch_bounds__(256)
void k_feat0(const bf16_t* __restrict__ keyb, float* __restrict__ out)
{
    int chunk = blockIdx.x, b = blockIdx.y;
    int tid = threadIdx.x, c = tid & 63, g = tid >> 6;
    const bf16_t* kb = keyb + (size_t)(b*16)*65536;
    float s = 0.f;
    for (int k = 0; k < 16; k++) {
        int p = chunk*64 + g*16 + k;
        s += (float)kb[(size_t)p*64 + c];
    }
    __shared__ float red[4][64];
    red[g][c] = s;
    __syncthreads();
    if (g == 0)
        atomicAdd(&out[(size_t)b*1024 + c],
                  (red[0][c]+red[1][c]+red[2][c]+red[3][c])*(1.f/1024.f));
}

// ---------------- feats t=1..15: weighted mean reduce ----------------
__global__ __launch_bounds__(256)
void k_feats(const float* __restrict__ mh, float* __restrict__ out)
{
    int slot = blockIdx.x, b = blockIdx.y, t = slot + 1;
    int tid = threadIdx.x, c = tid & 63, g = tid >> 6;
    const float* base = mh + (size_t)(b*15 + slot)*1024*66;
    float s = 0.f, sm = 0.f;
    for (int p = g; p < 1024; p += 4) {
        s += base[(size_t)p*66 + c];
        if (c == 0) sm += base[(size_t)p*66 + 64];
    }
    __shared__ float red[4][64];
    __shared__ float redm[4];
    red[g][c] = s;
    if (c == 0) redm[g] = sm;
    __syncthreads();
    if (g == 0) {
        float tot  = red[0][c] + red[1][c] + red[2][c] + red[3][c];
        float totm = redm[0] + redm[1] + redm[2] + redm[3];
        out[(size_t)(b*16 + t)*64 + c] = tot / fmaxf(totm, 1e-6f);
    }
}

// ---------------- host launcher ----------------
extern "C" void kernel_launch(void* const* d_in, const int* in_sizes, int n_in,
                              void* d_out, int out_size, void* d_ws, size_t ws_size,
                              hipStream_t stream)
{
    (void)in_sizes; (void)n_in; (void)out_size;
    if (ws_size < ws_need*sizeof(float)) return;
    const float* frames = (const float*)d_in[0];
    const float* imask  = (const float*)d_in[1];
    const float* Wk   = (const float*)d_in[3];
    const float* Wsh  = (const float*)d_in[4];
    const float* Wse  = (const float*)d_in[5];
    const float* Wf   = (const float*)d_in[6];
    const float* Wv   = (const float*)d_in[7];
    const float* Wh2  = (const float*)d_in[8];
    const float* Whd  = (const float*)d_in[9];
    const float* Wdec = (const float*)d_in[10];
    float* out = (float*)d_out;
    float* ws  = (float*)d_ws;

    bf16_t* wcatT = (bf16_t*)(ws + o_wcatT);
    bf16_t* whfT  = (bf16_t*)(ws + o_whfT);
    bf16_t* wvhT  = (bf16_t*)(ws + o_wvhT);
    float*  wvh1  = ws + o_wvh1;
    bf16_t* WvT   = (bf16_t*)(ws + o_WvT);
    float*  whh   = ws + o_whh;
    bf16_t* wh2T  = (bf16_t*)(ws + o_wh2T);
    bf16_t* keyb  = (bf16_t*)(ws + o_keyb);
    float*  msb   = ws + o_ms;
    bf16_t* qeb   = (bf16_t*)(ws + o_qeb);
    bf16_t* f16b  = (bf16_t*)(ws + o_f16b);
    bf16_t* qfb   = (bf16_t*)(ws + o_qfb);
    bf16_t* kfb   = (bf16_t*)(ws + o_kfb);
    bf16_t* vb    = (bf16_t*)(ws + o_vb);
    bf16_t* vhT   = (bf16_t*)(ws + o_vhT);
    float*  PVp   = ws + o_pv;
    bf16_t* p16b  = (bf16_t*)(ws + o_p16);
    float*  mh    = ws + o_mh;
    float*  hid   = ws + o_hid;
    float*  wmk   = ws + o_wmk;

    k_init<<<2145, 256, 0, stream>>>(Wk, Wsh, Wse, Wf, Wv, Wh2, Whd, Wdec,
                                     wcatT, whfT, WvT, whh, wh2T, out);
    k_wfuse<<<81, 256, 0, stream>>>(Wv, Whd, Wdec, wvhT, wvh1);
    k_proj<<<dim3(32,32), 256, 0, stream>>>(frames, wcatT, keyb, msb, qeb, f16b);
    k_qf<<<dim3(32,128), dim3(64,8), 0, stream>>>(keyb, qeb, qfb);
    k_mask0<<<64, 256, 0, stream>>>(imask, wmk);
    k_prep<<<dim3(16,2), 256, 0, stream>>>(f16b, keyb, msb, wmk, wvhT, wvh1, kfb, vhT, 0, 0);
    k_value<<<dim3(8,16,2), 256, 0, stream>>>(f16b, wmk, WvT, Wv, vb, 0, 0);
    k_hidm<<<dim3(16,2), 256, 0, stream>>>(vb, wh2T, hid, 0, 0);
    k_feat0<<<dim3(16,2), 256, 0, stream>>>(keyb, out);
    k_pre16<<<dim3(16,32), 256, 0, stream>>>(f16b, whfT, p16b);

    for (int ph = 0; ph < 3; ph++) {
        int t0 = 1 + ph*5;
        int ns = (ph + 1)*4;            // N/256 slices: 4, 8, 12
        k_att<<<dim3(16,5,2*ns), 256, 0, stream>>>(qfb, kfb, vhT, PVp, t0);
        k_chain2<<<dim3(256,2), 256, 0, stream>>>(p16b, PVp, whh, hid, wmk, mh, t0, ph, ns);
        if (ph < 2) {
            int tm = t0 + 4, slot = ph + 1;
            k_prep<<<dim3(16,2), 256, 0, stream>>>(f16b, keyb, msb, wmk, wvhT, wvh1, kfb, vhT, tm, slot);
            if (ph == 1) {
                k_value<<<dim3(8,16,2), 256, 0, stream>>>(f16b, wmk, WvT, Wv, vb, tm, slot);
                k_hidm<<<dim3(16,2), 256, 0, stream>>>(vb, wh2T, hid, 2, 1);
            }
        }
    }
    k_feats<<<dim3(15,2), 256, 0, stream>>>(mh, out);
}

// Round 7
// 555.791 us; speedup vs baseline: 1.8985x; 1.0032x over previous
//
#include <hip/hip_runtime.h>
#include <cstdint>

typedef __bf16 bf16_t;
typedef __attribute__((ext_vector_type(8))) __bf16 bf16x8;
typedef __attribute__((ext_vector_type(4))) __bf16 bf16x4;
typedef __attribute__((ext_vector_type(4))) float f32x4;

#define MFMA16(a,b,c) __builtin_amdgcn_mfma_f32_16x16x32_bf16((a),(b),(c),0,0,0)

// ---------------- workspace offsets (float units) ----------------
constexpr size_t PVSTR   = (size_t)2*5*1024*72;  // one N-slice of PV partials
constexpr size_t o_wcatT = 0;                    // bf16 [448][768]
constexpr size_t o_whfT  = o_wcatT + 172032;     // bf16 [128][256]
constexpr size_t o_wvhT  = o_whfT  + 16384;      // bf16 [80][256]  fused Wv@Whv (transposed)
constexpr size_t o_wvh1  = o_wvhT  + 10240;      // f32  [65]  (mask-row of fused weight)
constexpr size_t o_WvT   = o_wvh1  + 80;         // bf16 [512][256]
constexpr size_t o_whh   = o_WvT   + 65536;      // f32  [64][66]
constexpr size_t o_wh2T  = o_whh   + 4224;       // bf16 [64][576]
constexpr size_t o_keyb  = o_wh2T  + 18432;      // bf16 [B*T*1024][64]
constexpr size_t o_ms    = o_keyb  + 1048576;    // f32  [B*T*1024]
constexpr size_t o_qeb   = o_ms    + 32768;      // bf16 [B*T*1024][64]
constexpr size_t o_f16b  = o_qeb   + 1048576;    // bf16 [B*T*1024][256]
constexpr size_t o_qfb   = o_f16b  + 4194304;    // bf16 [B*T*1024][160]
constexpr size_t o_kfb   = o_qfb   + 2621440;    // bf16 [B*3072][160]
constexpr size_t o_vb    = o_kfb   + 491520;     // bf16 [B*3072][512] (slots 0,2 used)
constexpr size_t o_vhT   = o_vb    + 1572864;    // bf16 [B][128][3072] (row65 = ones)
constexpr size_t o_pv    = o_vhT   + 393216;     // f32  [12 slices][B][5][1024][72]
constexpr size_t o_p16   = o_pv    + 12*PVSTR;   // bf16 [B*T*1024][72]
constexpr size_t o_mh    = o_p16   + 1179648;    // f32  [B][15][1024][66]
constexpr size_t o_hid   = o_mh    + 2027520;    // f32  [B][1024][64]
constexpr size_t o_wmk   = o_hid   + 131072;     // f32  [B][1024]
constexpr size_t ws_need = o_wmk   + 2048;

// ---------------- init: transposed bf16 weight panels + zero out[t=0] ----------------
__global__ __launch_bounds__(256)
void k_init(const float* __restrict__ Wk, const float* __restrict__ Wsh,
            const float* __restrict__ Wse, const float* __restrict__ Wf,
            const float* __restrict__ Wv, const float* __restrict__ Wh2,
            const float* __restrict__ Whd, const float* __restrict__ Wdec,
            bf16_t* __restrict__ wcatT, bf16_t* __restrict__ whfT,
            bf16_t* __restrict__ WvT, float* __restrict__ whh,
            bf16_t* __restrict__ wh2T, float* __restrict__ out)
{
    int idx = blockIdx.x*256 + threadIdx.x;
    if (idx < 344064) {                       // wcatT[n][k] n<448 k<768
        int n = idx/768, k = idx%768;
        float v = 0.f;
        if (n < 64)       v = Wk[k*64+n];
        else if (n == 64) v = Wsh[k];
        else if (n < 129) v = Wse[k*64+(n-65)];
        else if (n < 385) v = Wf[k*256+(n-129)];
        wcatT[idx] = (bf16_t)v;
        return;
    }
    idx -= 344064;
    if (idx < 32768) {                        // whfT[c][k] c<128 k<256
        int c = idx/256, k = idx%256;
        float v = 0.f;
        if (c < 64) v = Whd[k*64+c]; else if (c == 64) v = Wdec[k];
        whfT[idx] = (bf16_t)v;
        return;
    }
    idx -= 32768;
    if (idx < 131072) {                       // WvT[n][k] n<512 k<256
        int n = idx/256, k = idx%256;
        WvT[idx] = (bf16_t)Wv[k*512+n];
        return;
    }
    idx -= 131072;
    if (idx < 4224) {                         // whh[k][c] (stride 66), c<65 real
        int k = idx/66, c = idx%66;
        float v = 0.f;
        if (c < 64) v = Whd[(768+k)*64+c]; else if (c == 64) v = Wdec[768+k];
        whh[idx] = v;
        return;
    }
    idx -= 4224;
    if (idx < 36864) {                        // wh2T[c][k] c<64 k<576
        int c = idx/576, k = idx%576;
        wh2T[idx] = (bf16_t)Wh2[k*64+c];
        return;
    }
    idx -= 36864;
    if (idx < 128) {                          // zero out[t=0] (feat0 atomics)
        int b = idx>>6, c = idx&63;
        out[(size_t)b*1024 + c] = 0.f;
    }
}

// ---------------- fused weight: Wvh[k][c] = Wv[k]@whv(:,c); wvh1 = Wv[256]@whv ----------------
// grid 81, block 256. whv(j,c) = Whd[(256+j)*64+c] (c<64) | Wdec[256+j] (c==64)
__global__ __launch_bounds__(256)
void k_wfuse(const float* __restrict__ Wv, const float* __restrict__ Whd,
             const float* __restrict__ Wdec, bf16_t* __restrict__ wvhT,
             float* __restrict__ wvh1)
{
    int idx = blockIdx.x*256 + threadIdx.x;
    if (idx < 20480) {
        int k = idx / 80, c = idx % 80;
        float s = 0.f;
        if (c < 65) {
            for (int j = 0; j < 512; j++) {
                float hv = (c < 64) ? Whd[(256+j)*64 + c] : Wdec[256 + j];
                s = fmaf(Wv[k*512 + j], hv, s);
            }
        }
        wvhT[(size_t)c*256 + k] = (bf16_t)s;
        return;
    }
    idx -= 20480;
    if (idx < 65) {
        int c = idx;
        float s = 0.f;
        for (int j = 0; j < 512; j++) {
            float hv = (c < 64) ? Whd[(256+j)*64 + c] : Wdec[256 + j];
            s = fmaf(Wv[256*512 + j], hv, s);
        }
        wvh1[c] = s;
    }
}

// ---------------- projection GEMM v2: 32-row tiles, dbuf LDS, 1 barrier/chunk ----------------
// grid (32 ptile, 32 bt), block 256 (4 waves). tile 32 rows x 448 cols, 24 K-chunks of 32.
__global__ __launch_bounds__(256)
void k_proj(const float* __restrict__ frames, const bf16_t* __restrict__ wcatT,
            bf16_t* __restrict__ keyb, float* __restrict__ msb,
            bf16_t* __restrict__ qeb, bf16_t* __restrict__ f16b)
{
    const int bx = blockIdx.x, bt = blockIdx.y;
    const int p0 = bx*32;
    const int tid = threadIdx.x, lane = tid & 63, w = tid >> 6;
    const int l15 = lane & 15, l4 = lane >> 4;
    __shared__ __align__(16) bf16_t Al[2][32][40];
    f32x4 acc[2][7] = {};
    const float* fb = frames + (size_t)bt*786432;
    // loader: thread -> (r = image-row parity, x4 = 4 consecutive floats of 512-row)
    const int r = tid >> 7, xx = tid & 127, x4 = xx*4;
    const int j = xx >> 2, pj = (xx & 3)*4;     // LDS row j (position), col r*16+pj
    const int ybase = bx*16 + r;

    #define PROJ_ADDR(kc) ((const float4*)(fb + (size_t)((kc)>>3)*262144 + \
        (size_t)(ybase + (((kc)*32 & 255) >> 4))*512 + x4))
    #define PROJ_STORE(buf, v) { bf16x4 pk; pk[0]=(bf16_t)(v).x; pk[1]=(bf16_t)(v).y; \
        pk[2]=(bf16_t)(v).z; pk[3]=(bf16_t)(v).w; *(bf16x4*)&Al[buf][j][r*16+pj] = pk; }
    #define PROJ_MFMA(buf, kc) { \
        bf16x8 a0 = *(const bf16x8*)&Al[buf][l15][l4*8]; \
        bf16x8 a1 = *(const bf16x8*)&Al[buf][16+l15][l4*8]; \
        _Pragma("unroll") \
        for (int fj = 0; fj < 7; fj++) { \
            int n = w*112 + fj*16 + l15; \
            bf16x8 bv = *(const bf16x8*)(wcatT + (size_t)n*768 + (kc)*32 + l4*8); \
            acc[0][fj] = MFMA16(a0, bv, acc[0][fj]); \
            acc[1][fj] = MFMA16(a1, bv, acc[1][fj]); \
        } }

    float4 nx0 = *PROJ_ADDR(0);
    float4 nx1 = *PROJ_ADDR(1);
    PROJ_STORE(0, nx0);
    for (int kc = 0; kc < 24; kc += 2) {
        __syncthreads();                       // buf0 (chunk kc) ready
        if (kc+2 < 24) nx0 = *PROJ_ADDR(kc+2);
        PROJ_MFMA(0, kc);
        PROJ_STORE(1, nx1);                    // buf1 <- chunk kc+1
        __syncthreads();
        if (kc+3 < 24) nx1 = *PROJ_ADDR(kc+3);
        PROJ_MFMA(1, kc+1);
        if (kc+2 < 24) PROJ_STORE(0, nx0);     // buf0 <- chunk kc+2
    }
    #undef PROJ_ADDR
    #undef PROJ_STORE
    #undef PROJ_MFMA

    #pragma unroll
    for (int fi = 0; fi < 2; fi++)
    #pragma unroll
    for (int fj = 0; fj < 7; fj++) {
        int nn = w*112 + fj*16 + l15;
        #pragma unroll
        for (int rr = 0; rr < 4; rr++) {
            int pp = p0 + fi*16 + l4*4 + rr;
            float v = acc[fi][fj][rr];
            size_t rowb = (size_t)bt*1024 + pp;
            if (nn < 64)       keyb[rowb*64 + nn] = (bf16_t)v;
            else if (nn == 64) msb[rowb] = v*v + 1.f;
            else if (nn < 129) qeb[rowb*64 + (nn-65)] = (bf16_t)(1.f/(1.f+expf(-v)));
            else if (nn < 385) f16b[rowb*256 + (nn-129)] = (bf16_t)v;
        }
    }
}

// ---------------- Qfeat: [qe*qk | qe | b_sq | zeros] bf16 ----------------
__global__ __launch_bounds__(512)
void k_qf(const bf16_t* __restrict__ keyb, const bf16_t* __restrict__ qeb,
          bf16_t* __restrict__ qfb)
{
    int bt = blockIdx.x;
    int p = blockIdx.y*8 + threadIdx.y;
    int c = threadIdx.x;
    size_t rowb = (size_t)bt*1024 + p;
    float qk = (float)keyb[rowb*64 + c];
    float qv = (float)qeb[rowb*64 + c];
    float bsq = qv*qk*qk;
    #pragma unroll
    for (int off = 32; off; off >>= 1) bsq += __shfl_xor(bsq, off);
    bf16_t* q = qfb + rowb*160;
    q[c]      = (bf16_t)(qv*qk);
    q[64 + c] = (bf16_t)qv;
    if (c == 0) q[128] = (bf16_t)bsq;
    if (c < 31) q[129 + c] = (bf16_t)0.f;
}

// ---------------- t=0 mask: aggregate + 16x16 avg-pool (coalesced) ----------------
__global__ __launch_bounds__(256)
void k_mask0(const float* __restrict__ im, float* __restrict__ wmask)
{
    int blk = blockIdx.x;
    int b = blk >> 5, i = blk & 31;
    int tid = threadIdx.x;
    int xq = tid & 127, yh = tid >> 7;
    const float* base = im + (size_t)b*262144 + (size_t)(i*16)*512;
    float s = 0.f;
    for (int yy = 0; yy < 8; yy++) {
        int y = yy*2 + yh;
        float4 v = *(const float4*)(base + (size_t)y*512 + xq*4);
        float e[4] = {v.x, v.y, v.z, v.w};
        #pragma unroll
        for (int u = 0; u < 4; u++) {
            float pc = fminf(fmaxf(e[u],      1e-7f), 1.f-1e-7f);
            float qc = fminf(fmaxf(1.f-e[u],  1e-7f), 1.f-1e-7f);
            s += pc*pc/(pc*pc + qc*qc);
        }
    }
    __shared__ float red[32];
    if (tid < 32) red[tid] = 0.f;
    __syncthreads();
    atomicAdd(&red[xq >> 2], s);
    __syncthreads();
    if (tid < 32) wmask[b*1024 + i*32 + tid] = red[tid]*(1.f/256.f);
}

// ---------------- per-slot prep: kf rows + vhT GEMM (from f16 + fused weight) ----------------
// grid (16, 2), block 256 (4 waves). vhT[c][n] = f16@Wvh + wmask*wvh1; row65=1.
__global__ __launch_bounds__(256)
void k_prep(const bf16_t* __restrict__ f16b, const bf16_t* __restrict__ keyb,
            const float* __restrict__ msb, const float* __restrict__ wmk,
            const bf16_t* __restrict__ wvhT, const float* __restrict__ wvh1,
            bf16_t* __restrict__ kfb, bf16_t* __restrict__ vhT, int tm, int slot)
{
    int b = blockIdx.y, n0 = blockIdx.x*64;
    int tid = threadIdx.x, lane = tid & 63, w = tid >> 6;
    // ---- kf fill (independent of GEMM) ----
    {
        int row = n0 + (tid >> 2), q = tid & 3;
        size_t rowb = (size_t)(b*16 + tm)*1024 + row;
        float m = msb[rowb];
        bf16_t* kr = kfb + ((size_t)b*3072 + slot*1024 + row)*160;
        bf16x8 k0v = *(const bf16x8*)(keyb + rowb*64 + q*16);
        bf16x8 k1v = *(const bf16x8*)(keyb + rowb*64 + q*16 + 8);
        bf16x8 o0, o1, s0, s1;
        #pragma unroll
        for (int u = 0; u < 8; u++) {
            float mk0 = (float)k0v[u], mk1 = (float)k1v[u];
            o0[u] = (bf16_t)( m*mk0*0.25f);       o1[u] = (bf16_t)( m*mk1*0.25f);
            s0[u] = (bf16_t)(-m*mk0*mk0*0.125f);  s1[u] = (bf16_t)(-m*mk1*mk1*0.125f);
        }
        *(bf16x8*)(kr + q*16)      = o0;  *(bf16x8*)(kr + q*16 + 8)      = o1;
        *(bf16x8*)(kr + 64 + q*16) = s0;  *(bf16x8*)(kr + 64 + q*16 + 8) = s1;
        if (q == 0) kr[128] = (bf16_t)(-m*0.125f);
        else if (q == 1) { for (int u = 0; u < 15; u++) kr[129+u] = (bf16_t)0.f; }
        else if (q == 2) { for (int u = 0; u < 16; u++) kr[144+u] = (bf16_t)0.f; }
    }
    // ---- vh GEMM: 64 n-rows x 80 c, K=256 ----
    int l15 = lane & 15, l4 = lane >> 4;
    const bf16_t* A = f16b + ((size_t)(b*16 + tm)*1024 + n0 + w*16 + l15)*256;
    f32x4 acc[5] = {};
    #pragma unroll
    for (int ks = 0; ks < 8; ks++) {
        bf16x8 a0 = *(const bf16x8*)(A + ks*32 + l4*8);
        #pragma unroll
        for (int cf = 0; cf < 5; cf++) {
            bf16x8 bv = *(const bf16x8*)(wvhT + (size_t)(cf*16 + l15)*256 + ks*32 + l4*8);
            acc[cf] = MFMA16(a0, bv, acc[cf]);
        }
    }
    #pragma unroll
    for (int cf = 0; cf < 5; cf++) {
        int cc = cf*16 + l15;
        float w1 = (cc < 65) ? wvh1[cc] : 0.f;
        #pragma unroll
        for (int rr = 0; rr < 4; rr++) {
            int p = n0 + w*16 + l4*4 + rr;
            float val;
            if (cc < 65)      val = acc[cf][rr] + wmk[b*1024 + p]*w1;
            else              val = (cc == 65) ? 1.f : 0.f;
            vhT[(size_t)b*393216 + (size_t)cc*3072 + slot*1024 + p] = (bf16_t)val;
        }
    }
}

// ---------------- value (MFMA): V = f16 @ Wv[0:256] + wmask*Wv[256] (slots 0,2) ----------------
__global__ __launch_bounds__(256)
void k_value(const bf16_t* __restrict__ f16b, const float* __restrict__ wmk,
             const bf16_t* __restrict__ WvT, const float* __restrict__ Wv,
             bf16_t* __restrict__ vb, int t, int slot)
{
    int b = blockIdx.z;
    int n0 = blockIdx.x*64, p0 = blockIdx.y*64;
    const int tid = threadIdx.x, lane = tid & 63, w = tid >> 6;
    const int wr = w >> 1, wc = w & 1, l15 = lane & 15, l4 = lane >> 4;
    const bf16_t* A = f16b + ((size_t)(b*16 + t)*1024 + p0)*256;
    f32x4 acc[2][2] = {};
    int ar = wr*32 + l15, bc = n0 + wc*32 + l15, koff = l4*8;
    #pragma unroll
    for (int ks = 0; ks < 8; ks++) {
        bf16x8 a0 = *(const bf16x8*)(A + (size_t)ar*256 + ks*32 + koff);
        bf16x8 a1 = *(const bf16x8*)(A + (size_t)(ar+16)*256 + ks*32 + koff);
        bf16x8 b0 = *(const bf16x8*)(WvT + (size_t)bc*256 + ks*32 + koff);
        bf16x8 b1 = *(const bf16x8*)(WvT + (size_t)(bc+16)*256 + ks*32 + koff);
        acc[0][0] = MFMA16(a0, b0, acc[0][0]);
        acc[0][1] = MFMA16(a0, b1, acc[0][1]);
        acc[1][0] = MFMA16(a1, b0, acc[1][0]);
        acc[1][1] = MFMA16(a1, b1, acc[1][1]);
    }
    #pragma unroll
    for (int fi = 0; fi < 2; fi++)
    #pragma unroll
    for (int fj = 0; fj < 2; fj++) {
        int nn = n0 + wc*32 + fj*16 + l15;
        float wvl = Wv[131072 + nn];
        #pragma unroll
        for (int rr = 0; rr < 4; rr++) {
            int pp = p0 + wr*32 + fi*16 + l4*4 + rr;
            float wm = wmk[b*1024 + pp];
            vb[((size_t)b*3072 + slot*1024 + pp)*512 + nn] = (bf16_t)(acc[fi][fj][rr] + wm*wvl);
        }
    }
}

// ---------------- pre16 (MFMA): f16 @ [Whd_lo|Wdec_lo] -> [p][65] ----------------
__global__ __launch_bounds__(256)
void k_pre16(const bf16_t* __restrict__ f16b, const bf16_t* __restrict__ whfT,
             bf16_t* __restrict__ p16b)
{
    int bt = blockIdx.y;
    int p0 = blockIdx.x*64;
    const int tid = threadIdx.x, lane = tid & 63, w = tid >> 6;
    const int wr = w >> 1, wc = w & 1, l15 = lane & 15, l4 = lane >> 4;
    const bf16_t* A = f16b + ((size_t)bt*1024 + p0)*256;
    f32x4 acc[2][4] = {};
    int ar = wr*32 + l15, koff = l4*8;
    #pragma unroll
    for (int ks = 0; ks < 8; ks++) {
        bf16x8 a0 = *(const bf16x8*)(A + (size_t)ar*256 + ks*32 + koff);
        bf16x8 a1 = *(const bf16x8*)(A + (size_t)(ar+16)*256 + ks*32 + koff);
        #pragma unroll
        for (int fj = 0; fj < 4; fj++) {
            int cc = wc*64 + fj*16 + l15;
            bf16x8 bv = *(const bf16x8*)(whfT + (size_t)cc*256 + ks*32 + koff);
            acc[0][fj] = MFMA16(a0, bv, acc[0][fj]);
            acc[1][fj] = MFMA16(a1, bv, acc[1][fj]);
        }
    }
    #pragma unroll
    for (int fi = 0; fi < 2; fi++)
    #pragma unroll
    for (int fj = 0; fj < 4; fj++) {
        int cc = wc*64 + fj*16 + l15;
        if (cc < 65) {
            #pragma unroll
            for (int rr = 0; rr < 4; rr++) {
                int pp = p0 + wr*32 + fi*16 + l4*4 + rr;
                p16b[((size_t)bt*1024 + pp)*72 + cc] = (bf16_t)acc[fi][fj][rr];
            }
        }
    }
}

// ---------------- split-N attention: exp(S)·Vh partials (sim<=0, no max/sum) ----------------
__global__ __launch_bounds__(256)
void k_att(const bf16_t* __restrict__ qfb, const bf16_t* __restrict__ kfb,
           const bf16_t* __restrict__ vhT, float* __restrict__ PVp, int t0)
{
    int b = blockIdx.z & 1, sl = blockIdx.z >> 1;
    int ts = blockIdx.y, t = t0 + ts, p0 = blockIdx.x*64;
    int n_base = sl*256;
    int tid = threadIdx.x, lane = tid & 63, w = tid >> 6;
    int l15 = lane & 15, l4 = lane >> 4;
    __shared__ __align__(16) bf16_t P_lds[4][16][72];

    const bf16_t* Q = qfb + ((size_t)(b*16 + t)*1024 + p0 + w*16 + l15)*160 + l4*8;
    bf16x8 aq[5];
    #pragma unroll
    for (int kc = 0; kc < 5; kc++) aq[kc] = *(const bf16x8*)(Q + kc*32);

    const bf16_t* K  = kfb + ((size_t)b*3072 + n_base)*160;
    const bf16_t* Vh = vhT + (size_t)b*393216 + n_base;
    f32x4 o[5] = {};

    for (int n0 = 0; n0 < 256; n0 += 64) {
        f32x4 s[4] = {};
        #pragma unroll
        for (int kc = 0; kc < 5; kc++) {
            #pragma unroll
            for (int nf = 0; nf < 4; nf++) {
                bf16x8 bk = *(const bf16x8*)(K + (size_t)(n0 + nf*16 + l15)*160 + kc*32 + l4*8);
                s[nf] = MFMA16(aq[kc], bk, s[nf]);
            }
        }
        #pragma unroll
        for (int nf = 0; nf < 4; nf++) {
            #pragma unroll
            for (int rr = 0; rr < 4; rr++) {
                float pe = __expf(s[nf][rr]);
                P_lds[w][l4*4 + rr][nf*16 + l15] = (bf16_t)pe;
            }
        }
        #pragma unroll
        for (int kc2 = 0; kc2 < 2; kc2++) {
            bf16x8 ap = *(const bf16x8*)&P_lds[w][l15][kc2*32 + l4*8];
            #pragma unroll
            for (int cf = 0; cf < 5; cf++) {
                bf16x8 bv = *(const bf16x8*)(Vh + (size_t)(cf*16 + l15)*3072 + n0 + kc2*32 + l4*8);
                o[cf] = MFMA16(ap, bv, o[cf]);
            }
        }
    }
    float* O = PVp + (size_t)sl*PVSTR + ((size_t)((b*5 + ts)*1024) + p0 + w*16)*72;
    #pragma unroll
    for (int cf = 0; cf < 5; cf++) {
        int cc = cf*16 + l15;
        if (cc < 66) {
            #pragma unroll
            for (int rr = 0; rr < 4; rr++)
                O[(size_t)(l4*4 + rr)*72 + cc] = o[cf][rr];
        }
    }
}

// ---------------- sequential 5-step chain; sums PV slices, divides by col65 ----------------
__global__ __launch_bounds__(256)
void k_chain2(const bf16_t* __restrict__ p16b, const float* __restrict__ PVp,
              const float* __restrict__ whhbuf, float* __restrict__ hidden,
              float* __restrict__ wmk, float* __restrict__ mh, int t0, int ph, int ns)
{
    int b = blockIdx.y;
    int tid = threadIdx.x, lane = tid & 63, w = tid >> 6;
    int p = blockIdx.x*4 + w;
    __shared__ float whh_s[64][66];
    __shared__ float hid_s[4][64];
    for (int idx = tid; idx < 64*66; idx += 256) whh_s[idx/66][idx%66] = whhbuf[idx];
    float h = hidden[((size_t)b*1024 + p)*64 + lane];
    hid_s[w][lane] = h;
    __syncthreads();
    float wd = whh_s[lane][64];
    for (int ts = 0; ts < 5; ts++) {
        int t = t0 + ts;
        size_t r16 = ((size_t)(b*16 + t)*1024 + p)*72;
        size_t rpv = ((size_t)((b*5 + ts)*1024) + p)*72;
        float pvc = 0.f, pv64 = 0.f, pv65 = 0.f;
        for (int s2 = 0; s2 < ns; s2++) {
            const float* bp = PVp + (size_t)s2*PVSTR + rpv;
            pvc  += bp[lane];
            pv64 += bp[64];
            pv65 += bp[65];
        }
        float rinv  = 1.f/pv65;
        float pre   = (float)p16b[r16 + lane] + pvc*rinv;
        float fgpre = (float)p16b[r16 + 64]   + pv64*rinv;
        float s = pre;
        #pragma unroll 8
        for (int k = 0; k < 64; k++) s += hid_s[w][k]*whh_s[k][lane];
        float hl = tanhf(s);
        float fgs = hl*wd;
        #pragma unroll
        for (int off = 1; off < 64; off <<= 1) fgs += __shfl_xor(fgs, off);
        float fg = fgpre + fgs;
        float m = 1.f/(1.f+expf(-fg));
        size_t rmh = ((size_t)(b*15 + ph*5 + ts)*1024 + p)*66;
        mh[rmh + lane] = m*hl;
        if (lane == 0) mh[rmh + 64] = m;
        if (ts == 4 && lane == 0) wmk[b*1024 + p] = m;
        h = hl;
        __syncthreads();
        hid_s[w][lane] = h;
        __syncthreads();
    }
    hidden[((size_t)b*1024 + p)*64 + lane] = h;
}

// ---------------- hidden update (MFMA): tanh([V | hid?] @ Wh2) ----------------
// grid (16, 2), block 256 (4 waves); K = 512 (+64 when has_h)
__global__ __launch_bounds__(256)
void k_hidm(const bf16_t* __restrict__ vb, const bf16_t* __restrict__ wh2T,
            float* __restrict__ hidden, int vslot, int has_h)
{
    int b = blockIdx.y, p0 = blockIdx.x*64;
    int tid = threadIdx.x, lane = tid & 63, w = tid >> 6;
    int l15 = lane & 15, l4 = lane >> 4;
    int arow = p0 + w*16 + l15;
    const bf16_t* A = vb + ((size_t)b*3072 + vslot*1024 + arow)*512;
    const float* Hp = hidden + ((size_t)b*1024 + arow)*64;
    f32x4 acc[4] = {};
    int kiters = has_h ? 18 : 16;
    for (int ks = 0; ks < kiters; ks++) {
        bf16x8 a0;
        if (ks < 16) a0 = *(const bf16x8*)(A + ks*32 + l4*8);
        else {
            int ko = (ks-16)*32 + l4*8;
            float4 h0 = *(const float4*)(Hp + ko);
            float4 h1 = *(const float4*)(Hp + ko + 4);
            a0[0]=(bf16_t)h0.x; a0[1]=(bf16_t)h0.y; a0[2]=(bf16_t)h0.z; a0[3]=(bf16_t)h0.w;
            a0[4]=(bf16_t)h1.x; a0[5]=(bf16_t)h1.y; a0[6]=(bf16_t)h1.z; a0[7]=(bf16_t)h1.w;
        }
        #pragma unroll
        for (int cf = 0; cf < 4; cf++) {
            bf16x8 bv = *(const bf16x8*)(wh2T + (size_t)(cf*16 + l15)*576 + ks*32 + l4*8);
            acc[cf] = MFMA16(a0, bv, acc[cf]);
        }
    }
    #pragma unroll
    for (int cf = 0; cf < 4; cf++) {
        int cc = cf*16 + l15;
        #pragma unroll
        for (int rr = 0; rr < 4; rr++) {
            int p = p0 + w*16 + l4*4 + rr;
            hidden[((size_t)b*1024 + p)*64 + cc] = tanhf(acc[cf][rr]);
        }
    }
}

// ---------------- feat t=0: mean over spatial of key (parallel + atomic) ----------------
// grid (16, 2), block 256
__global__ __launch_bounds__(256)
void k_feat0(const bf16_t* __restrict__ keyb, float* __restrict__ out)
{
    int chunk = blockIdx.x, b = blockIdx.y;
    int tid = threadIdx.x, c = tid & 63, g = tid >> 6;
    const bf16_t* kb = keyb + (size_t)(b*16)*65536;
    float s = 0.f;
    for (int k = 0; k < 16; k++) {
        int p = chunk*64 + g*16 + k;
        s += (float)kb[(size_t)p*64 + c];
    }
    __shared__ float red[4][64];
    red[g][c] = s;
    __syncthreads();
    if (g == 0)
        atomicAdd(&out[(size_t)b*1024 + c],
                  (red[0][c]+red[1][c]+red[2][c]+red[3][c])*(1.f/1024.f));
}

// ---------------- feats t=1..15: weighted mean reduce ----------------
__global__ __launch_bounds__(256)
void k_feats(const float* __restrict__ mh, float* __restrict__ out)
{
    int slot = blockIdx.x, b = blockIdx.y, t = slot + 1;
    int tid = threadIdx.x, c = tid & 63, g = tid >> 6;
    const float* base = mh + (size_t)(b*15 + slot)*1024*66;
    float s = 0.f, sm = 0.f;
    for (int p = g; p < 1024; p += 4) {
        s += base[(size_t)p*66 + c];
        if (c == 0) sm += base[(size_t)p*66 + 64];
    }
    __shared__ float red[4][64];
    __shared__ float redm[4];
    red[g][c] = s;
    if (c == 0) redm[g] = sm;
    __syncthreads();
    if (g == 0) {
        float tot  = red[0][c] + red[1][c] + red[2][c] + red[3][c];
        float totm = redm[0] + redm[1] + redm[2] + redm[3];
        out[(size_t)(b*16 + t)*64 + c] = tot / fmaxf(totm, 1e-6f);
    }
}

// ---------------- host launcher ----------------
extern "C" void kernel_launch(void* const* d_in, const int* in_sizes, int n_in,
                              void* d_out, int out_size, void* d_ws, size_t ws_size,
                              hipStream_t stream)
{
    (void)in_sizes; (void)n_in; (void)out_size;
    if (ws_size < ws_need*sizeof(float)) return;
    const float* frames = (const float*)d_in[0];
    const float* imask  = (const float*)d_in[1];
    const float* Wk   = (const float*)d_in[3];
    const float* Wsh  = (const float*)d_in[4];
    const float* Wse  = (const float*)d_in[5];
    const float* Wf   = (const float*)d_in[6];
    const float* Wv   = (const float*)d_in[7];
    const float* Wh2  = (const float*)d_in[8];
    const float* Whd  = (const float*)d_in[9];
    const float* Wdec = (const float*)d_in[10];
    float* out = (float*)d_out;
    float* ws  = (float*)d_ws;

    bf16_t* wcatT = (bf16_t*)(ws + o_wcatT);
    bf16_t* whfT  = (bf16_t*)(ws + o_whfT);
    bf16_t* wvhT  = (bf16_t*)(ws + o_wvhT);
    float*  wvh1  = ws + o_wvh1;
    bf16_t* WvT   = (bf16_t*)(ws + o_WvT);
    float*  whh   = ws + o_whh;
    bf16_t* wh2T  = (bf16_t*)(ws + o_wh2T);
    bf16_t* keyb  = (bf16_t*)(ws + o_keyb);
    float*  msb   = ws + o_ms;
    bf16_t* qeb   = (bf16_t*)(ws + o_qeb);
    bf16_t* f16b  = (bf16_t*)(ws + o_f16b);
    bf16_t* qfb   = (bf16_t*)(ws + o_qfb);
    bf16_t* kfb   = (bf16_t*)(ws + o_kfb);
    bf16_t* vb    = (bf16_t*)(ws + o_vb);
    bf16_t* vhT   = (bf16_t*)(ws + o_vhT);
    float*  PVp   = ws + o_pv;
    bf16_t* p16b  = (bf16_t*)(ws + o_p16);
    float*  mh    = ws + o_mh;
    float*  hid   = ws + o_hid;
    float*  wmk   = ws + o_wmk;

    k_init<<<2145, 256, 0, stream>>>(Wk, Wsh, Wse, Wf, Wv, Wh2, Whd, Wdec,
                                     wcatT, whfT, WvT, whh, wh2T, out);
    k_wfuse<<<81, 256, 0, stream>>>(Wv, Whd, Wdec, wvhT, wvh1);
    k_proj<<<dim3(32,32), 256, 0, stream>>>(frames, wcatT, keyb, msb, qeb, f16b);
    k_qf<<<dim3(32,128), dim3(64,8), 0, stream>>>(keyb, qeb, qfb);
    k_mask0<<<64, 256, 0, stream>>>(imask, wmk);
    k_prep<<<dim3(16,2), 256, 0, stream>>>(f16b, keyb, msb, wmk, wvhT, wvh1, kfb, vhT, 0, 0);
    k_value<<<dim3(8,16,2), 256, 0, stream>>>(f16b, wmk, WvT, Wv, vb, 0, 0);
    k_hidm<<<dim3(16,2), 256, 0, stream>>>(vb, wh2T, hid, 0, 0);
    k_feat0<<<dim3(16,2), 256, 0, stream>>>(keyb, out);
    k_pre16<<<dim3(16,32), 256, 0, stream>>>(f16b, whfT, p16b);

    for (int ph = 0; ph < 3; ph++) {
        int t0 = 1 + ph*5;
        int ns = (ph + 1)*4;            // N/256 slices: 4, 8, 12
        k_att<<<dim3(16,5,2*ns), 256, 0, stream>>>(qfb, kfb, vhT, PVp, t0);
        k_chain2<<<dim3(256,2), 256, 0, stream>>>(p16b, PVp, whh, hid, wmk, mh, t0, ph, ns);
        if (ph < 2) {
            int tm = t0 + 4, slot = ph + 1;
            k_prep<<<dim3(16,2), 256, 0, stream>>>(f16b, keyb, msb, wmk, wvhT, wvh1, kfb, vhT, tm, slot);
            if (ph == 1) {
                k_value<<<dim3(8,16,2), 256, 0, stream>>>(f16b, wmk, WvT, Wv, vb, tm, slot);
                k_hidm<<<dim3(16,2), 256, 0, stream>>>(vb, wh2T, hid, 2, 1);
            }
        }
    }
    k_feats<<<dim3(15,2), 256, 0, stream>>>(mh, out);
}